// Round 1
// baseline (1409.053 us; speedup 1.0000x reference)
//
#include <hip/hip_runtime.h>
#include <cstdint>
#include <cstddef>

#define N_NODES 102400
#define N_EDGES 1638400
#define DIM 128

// ---------------------------------------------------------------------------
// CSR build: degree histogram
// ---------------------------------------------------------------------------
__global__ void k_hist(const int* __restrict__ esrc, const int* __restrict__ edst,
                       int* __restrict__ deg_src, int* __restrict__ deg_dst) {
  const int i = blockIdx.x * blockDim.x + threadIdx.x;
  if (i < N_EDGES) {
    atomicAdd(&deg_src[esrc[i]], 1);
    atomicAdd(&deg_dst[edst[i]], 1);
  }
}

// ---------------------------------------------------------------------------
// Single-block exclusive scan over deg_dst -> row_off/cursor, plus norms.
// N_NODES is divisible by 1024 so no bounds checks needed.
// ---------------------------------------------------------------------------
__global__ void k_scan(const int* __restrict__ deg_src, const int* __restrict__ deg_dst,
                       int* __restrict__ row_off, int* __restrict__ cursor,
                       float* __restrict__ src_norm, float* __restrict__ dst_norm) {
  __shared__ int wsum[16];
  const int tid  = threadIdx.x;
  const int lane = tid & 63;
  const int wid  = tid >> 6;
  int carry = 0;
  for (int base = 0; base < N_NODES; base += 1024) {
    const int i  = base + tid;
    const int d  = deg_dst[i];
    const int ds = deg_src[i];
    dst_norm[i] = 1.0f / sqrtf((float)(d  > 0 ? d  : 1));
    src_norm[i] = 1.0f / sqrtf((float)(ds > 0 ? ds : 1));

    // wave-level inclusive scan
    int v = d;
    #pragma unroll
    for (int off = 1; off < 64; off <<= 1) {
      const int t = __shfl_up(v, off);
      if (lane >= off) v += t;
    }
    if (lane == 63) wsum[wid] = v;
    __syncthreads();
    if (tid < 16) {
      int w = wsum[tid];
      #pragma unroll
      for (int off = 1; off < 16; off <<= 1) {
        const int t = __shfl_up(w, off);
        if (tid >= off) w += t;
      }
      wsum[tid] = w;  // inclusive over wave sums
    }
    __syncthreads();
    const int excl = carry + (wid > 0 ? wsum[wid - 1] : 0) + v - d;
    row_off[i] = excl;
    cursor[i]  = excl;
    const int total = wsum[15];
    __syncthreads();  // protect wsum before next chunk
    carry += total;
  }
  if (tid == 0) row_off[N_NODES] = carry;
}

// ---------------------------------------------------------------------------
// CSR fill (order within a row is arbitrary; sum is order-tolerant in f32)
// ---------------------------------------------------------------------------
__global__ void k_fill(const int* __restrict__ esrc, const int* __restrict__ edst,
                       int* __restrict__ cursor, int* __restrict__ csr_src) {
  const int i = blockIdx.x * blockDim.x + threadIdx.x;
  if (i < N_EDGES) {
    const int pos = atomicAdd(&cursor[edst[i]], 1);
    csr_src[pos] = esrc[i];
  }
}

// ---------------------------------------------------------------------------
// Fused GCN layer: aggregate 64 dst rows into LDS, then f32 GEMM @ W + bias
// + activation, store straight to the output slice.
// ACT: 0 = ELU, 1 = softmax over the 128-dim row
// ---------------------------------------------------------------------------
template <int ACT>
__global__ __launch_bounds__(256, 3) void k_layer(
    const float* __restrict__ feat, const float* __restrict__ W,
    const float* __restrict__ bias, const int* __restrict__ row_off,
    const int* __restrict__ csr_src, const float* __restrict__ src_norm,
    const float* __restrict__ dst_norm, float* __restrict__ out) {
  __shared__ float agg[64][132];   // +4 pad: keeps float4 alignment, breaks stride-128 banking
  __shared__ float Wl[32][128];    // one 32-row K-chunk of W

  const int tid  = threadIdx.x;
  const int lane = tid & 63;
  const int wid  = tid >> 6;
  const int brow = blockIdx.x * 64;

  // ---- phase 1: aggregation (wave per row, float2 per lane = 128 cols) ----
  for (int r = wid; r < 64; r += 4) {
    const int gr = brow + r;
    const int e0 = row_off[gr];
    const int e1 = row_off[gr + 1];
    float ax = 0.f, ay = 0.f;
    for (int e = e0; e < e1; e += 64) {
      const int cnt = min(64, e1 - e);
      int   idx = 0;
      float sn  = 0.f;
      if (lane < cnt) {
        idx = csr_src[e + lane];
        sn  = src_norm[idx];
      }
      #pragma unroll 4
      for (int j = 0; j < cnt; ++j) {
        const int   s = __builtin_amdgcn_readlane(idx, j);
        const float w = __int_as_float(
            __builtin_amdgcn_readlane(__float_as_int(sn), j));
        const float2 v =
            *reinterpret_cast<const float2*>(feat + (size_t)s * DIM + lane * 2);
        ax = fmaf(w, v.x, ax);
        ay = fmaf(w, v.y, ay);
      }
    }
    const float dn = dst_norm[gr];
    agg[r][lane * 2]     = ax * dn;
    agg[r][lane * 2 + 1] = ay * dn;
  }

  // ---- phase 2: out[64][128] = agg @ W, chunked over K ----
  const int tc = tid & 31;   // 32 col-groups of 4 cols
  const int tr = tid >> 5;   // 8 row-groups of 8 rows
  const int c0 = tc * 4;

  float4 acc[8];
  #pragma unroll
  for (int i = 0; i < 8; ++i) acc[i] = make_float4(0.f, 0.f, 0.f, 0.f);

  for (int kc = 0; kc < 4; ++kc) {
    __syncthreads();  // agg complete (kc=0) / previous chunk's reads done
    {
      const float4* Wg  = reinterpret_cast<const float4*>(W + kc * 32 * DIM);
      float4*       Wsh = reinterpret_cast<float4*>(&Wl[0][0]);
      #pragma unroll
      for (int t = 0; t < 4; ++t) Wsh[tid + t * 256] = Wg[tid + t * 256];
    }
    __syncthreads();
    #pragma unroll
    for (int k4 = 0; k4 < 32; k4 += 4) {
      float4 w4[4];
      #pragma unroll
      for (int j = 0; j < 4; ++j)
        w4[j] = *reinterpret_cast<const float4*>(&Wl[k4 + j][c0]);
      #pragma unroll
      for (int i = 0; i < 8; ++i) {
        const float4 a =
            *reinterpret_cast<const float4*>(&agg[tr * 8 + i][kc * 32 + k4]);
        const float av[4] = {a.x, a.y, a.z, a.w};
        #pragma unroll
        for (int j = 0; j < 4; ++j) {
          acc[i].x = fmaf(av[j], w4[j].x, acc[i].x);
          acc[i].y = fmaf(av[j], w4[j].y, acc[i].y);
          acc[i].z = fmaf(av[j], w4[j].z, acc[i].z);
          acc[i].w = fmaf(av[j], w4[j].w, acc[i].w);
        }
      }
    }
  }

  // ---- epilogue: bias + activation + store ----
  const float4 bv = *reinterpret_cast<const float4*>(bias + c0);
  #pragma unroll
  for (int i = 0; i < 8; ++i) {
    float4 v = acc[i];
    v.x += bv.x; v.y += bv.y; v.z += bv.z; v.w += bv.w;
    if (ACT == 0) {
      v.x = v.x > 0.f ? v.x : expm1f(v.x);
      v.y = v.y > 0.f ? v.y : expm1f(v.y);
      v.z = v.z > 0.f ? v.z : expm1f(v.z);
      v.w = v.w > 0.f ? v.w : expm1f(v.w);
    } else {
      // softmax across the 128 cols of this row (32 lanes x 4 cols)
      float m = fmaxf(fmaxf(v.x, v.y), fmaxf(v.z, v.w));
      #pragma unroll
      for (int off = 16; off >= 1; off >>= 1) m = fmaxf(m, __shfl_xor(m, off));
      v.x = expf(v.x - m);
      v.y = expf(v.y - m);
      v.z = expf(v.z - m);
      v.w = expf(v.w - m);
      float s = v.x + v.y + v.z + v.w;
      #pragma unroll
      for (int off = 16; off >= 1; off >>= 1) s += __shfl_xor(s, off);
      const float inv = 1.0f / s;
      v.x *= inv; v.y *= inv; v.z *= inv; v.w *= inv;
    }
    *reinterpret_cast<float4*>(out + (size_t)(brow + tr * 8 + i) * DIM + c0) = v;
  }
}

// ---------------------------------------------------------------------------
extern "C" void kernel_launch(void* const* d_in, const int* in_sizes, int n_in,
                              void* d_out, int out_size, void* d_ws,
                              size_t ws_size, hipStream_t stream) {
  const float* x  = (const float*)d_in[0];
  const float* W1 = (const float*)d_in[1];
  const float* b1 = (const float*)d_in[2];
  const float* W2 = (const float*)d_in[3];
  const float* b2 = (const float*)d_in[4];
  const float* W3 = (const float*)d_in[5];
  const float* b3 = (const float*)d_in[6];
  const int* esrc = (const int*)d_in[7];
  const int* edst = (const int*)d_in[8];

  char* ws = (char*)d_ws;
  int* deg_src = (int*)ws;  ws += (size_t)N_NODES * 4;
  int* deg_dst = (int*)ws;  ws += (size_t)N_NODES * 4;
  int* row_off = (int*)ws;  ws += (size_t)(N_NODES + 32) * 4;
  int* cursor  = (int*)ws;  ws += (size_t)N_NODES * 4;
  float* src_norm = (float*)ws;  ws += (size_t)N_NODES * 4;
  float* dst_norm = (float*)ws;  ws += (size_t)N_NODES * 4;
  int* csr_src = (int*)ws;  ws += (size_t)N_EDGES * 4;

  float* y1 = (float*)d_out;
  float* y2 = y1 + (size_t)N_NODES * DIM;
  float* y3 = y2 + (size_t)N_NODES * DIM;

  // deg_src & deg_dst are contiguous: one memset
  hipMemsetAsync(deg_src, 0, (size_t)N_NODES * 2 * sizeof(int), stream);

  k_hist<<<(N_EDGES + 255) / 256, 256, 0, stream>>>(esrc, edst, deg_src, deg_dst);
  k_scan<<<1, 1024, 0, stream>>>(deg_src, deg_dst, row_off, cursor, src_norm,
                                 dst_norm);
  k_fill<<<(N_EDGES + 255) / 256, 256, 0, stream>>>(esrc, edst, cursor, csr_src);

  k_layer<0><<<N_NODES / 64, 256, 0, stream>>>(x, W1, b1, row_off, csr_src,
                                               src_norm, dst_norm, y1);
  k_layer<0><<<N_NODES / 64, 256, 0, stream>>>(y1, W2, b2, row_off, csr_src,
                                               src_norm, dst_norm, y2);
  k_layer<1><<<N_NODES / 64, 256, 0, stream>>>(y2, W3, b3, row_off, csr_src,
                                               src_norm, dst_norm, y3);
}

// Round 2
// 809.502 us; speedup vs baseline: 1.7406x; 1.7406x over previous
//
#include <hip/hip_runtime.h>
#include <cstdint>
#include <cstddef>

#define N_NODES 102400
#define N_EDGES 1638400
#define DIM 128

// ---------------------------------------------------------------------------
// degree histograms
// ---------------------------------------------------------------------------
__global__ void k_hist(const int* __restrict__ esrc, const int* __restrict__ edst,
                       int* __restrict__ deg_src, int* __restrict__ deg_dst) {
  const int i = blockIdx.x * blockDim.x + threadIdx.x;
  if (i < N_EDGES) {
    atomicAdd(&deg_src[esrc[i]], 1);
    atomicAdd(&deg_dst[edst[i]], 1);
  }
}

// ---------------------------------------------------------------------------
// 100 blocks x 256: dst_norm + per-1024-node block sums of deg_dst
// ---------------------------------------------------------------------------
__global__ void k_bsum(const int* __restrict__ deg_dst, float* __restrict__ dst_norm,
                       int* __restrict__ bsum) {
  __shared__ int ws[4];
  const int tid  = threadIdx.x;
  const int base = blockIdx.x * 1024;
  int s = 0;
  #pragma unroll
  for (int t = 0; t < 4; ++t) {
    const int i = base + t * 256 + tid;
    const int d = deg_dst[i];
    s += d;
    dst_norm[i] = rsqrtf((float)(d > 0 ? d : 1));
  }
  #pragma unroll
  for (int off = 32; off >= 1; off >>= 1) s += __shfl_down(s, off);
  if ((tid & 63) == 0) ws[tid >> 6] = s;
  __syncthreads();
  if (tid == 0) bsum[blockIdx.x] = ws[0] + ws[1] + ws[2] + ws[3];
}

// ---------------------------------------------------------------------------
// 1 block x 128: exclusive scan of the 100 block sums
// ---------------------------------------------------------------------------
__global__ void k_bscan(const int* __restrict__ bsum, int* __restrict__ bpre) {
  const int tid = threadIdx.x;
  const int v = (tid < 100) ? bsum[tid] : 0;
  int s = v;
  #pragma unroll
  for (int off = 1; off < 64; off <<= 1) {
    const int t = __shfl_up(s, off);
    if ((tid & 63) >= off) s += t;
  }
  __shared__ int w0;
  if (tid == 63) w0 = s;
  __syncthreads();
  if (tid >= 64) s += w0;
  if (tid < 100) bpre[tid] = s - v;
}

// ---------------------------------------------------------------------------
// 100 blocks x 1024: block-local exclusive scan of deg_dst + bpre offset
// ---------------------------------------------------------------------------
__global__ void k_rowoff(const int* __restrict__ deg_dst, const int* __restrict__ bpre,
                         int* __restrict__ row_off, int* __restrict__ cursor) {
  __shared__ int wsum[16];
  const int tid  = threadIdx.x;
  const int lane = tid & 63;
  const int wid  = tid >> 6;
  const int i = blockIdx.x * 1024 + tid;
  const int d = deg_dst[i];
  int v = d;
  #pragma unroll
  for (int off = 1; off < 64; off <<= 1) {
    const int t = __shfl_up(v, off);
    if (lane >= off) v += t;
  }
  if (lane == 63) wsum[wid] = v;
  __syncthreads();
  if (tid < 16) {
    int w = wsum[tid];
    #pragma unroll
    for (int off = 1; off < 16; off <<= 1) {
      const int t = __shfl_up(w, off);
      if (tid >= off) w += t;
    }
    wsum[tid] = w;
  }
  __syncthreads();
  const int excl = bpre[blockIdx.x] + (wid > 0 ? wsum[wid - 1] : 0) + v - d;
  row_off[i] = excl;
  cursor[i]  = excl;
  if (i == N_NODES - 1) row_off[N_NODES] = excl + d;
}

// ---------------------------------------------------------------------------
// CSR fill, packed: byte-offset (26 bits) | min(deg_src,63) << 26
// ---------------------------------------------------------------------------
__global__ void k_fill(const int* __restrict__ esrc, const int* __restrict__ edst,
                       const int* __restrict__ deg_src, int* __restrict__ cursor,
                       unsigned* __restrict__ csr_pk) {
  const int i = blockIdx.x * blockDim.x + threadIdx.x;
  if (i < N_EDGES) {
    const int s  = esrc[i];
    const int dg = deg_src[s];
    const int pos = atomicAdd(&cursor[edst[i]], 1);
    csr_pk[pos] = ((unsigned)s << 9) | ((unsigned)(dg > 63 ? 63 : dg) << 26);
  }
}

// ---------------------------------------------------------------------------
// Fused GCN layer. 64-row tile; 2-edge-parallel half-wave gather (float4),
// next-row CSR prefetch; then f32 GEMM (W read direct from global, L2-hot).
// ACT: 0 = ELU, 1 = row softmax
// ---------------------------------------------------------------------------
template <int ACT>
__global__ __launch_bounds__(256, 4) void k_layer(
    const float* __restrict__ feat, const float* __restrict__ W,
    const float* __restrict__ bias, const int* __restrict__ row_off,
    const unsigned* __restrict__ csr_pk, const float* __restrict__ dst_norm,
    float* __restrict__ out) {
  __shared__ float agg[64][132];

  const int tid  = threadIdx.x;
  const int lane = tid & 63;
  const int wid  = tid >> 6;
  const int h    = lane >> 5;   // half-wave id (edge parity)
  const int l32  = lane & 31;   // 32 lanes x float4 = 128 cols
  const int brow = blockIdx.x * 64;
  const char* fbase = reinterpret_cast<const char*>(feat);

  // ---- phase 1: aggregation, 16 rows per wave, prefetched ----
  int gr = brow + wid;
  int e0 = row_off[gr];
  int e1 = row_off[gr + 1];
  unsigned pk0 = 0;
  {
    const int cnt = min(64, e1 - e0);
    if (lane < cnt) pk0 = csr_pk[e0 + lane];
  }

  for (int r = wid; r < 64; r += 4) {
    // prefetch next row's metadata + first CSR chunk
    int ne0 = 0, ne1 = 0;
    unsigned npk = 0;
    if (r + 4 < 64) {
      ne0 = row_off[gr + 4];
      ne1 = row_off[gr + 5];
      const int ncnt = min(64, ne1 - ne0);
      if (lane < ncnt) npk = csr_pk[ne0 + lane];
    }

    // process current row
    float4 acc = make_float4(0.f, 0.f, 0.f, 0.f);
    int e = e0;
    unsigned pk = pk0;
    while (true) {
      const int cnt = min(64, e1 - e);
      const int off = (int)(pk & 0x03FFFFFFu);
      const float w = (lane < cnt) ? rsqrtf((float)(pk >> 26)) : 0.0f;
      const int npair = (cnt + 1) >> 1;
      #pragma unroll 8
      for (int j = 0; j < npair; ++j) {
        const int srcl = 2 * j + h;
        const int o    = __shfl(off, srcl);
        const float ww = __shfl(w, srcl);
        const float4 v = *reinterpret_cast<const float4*>(
            fbase + (size_t)(unsigned)o + (l32 << 4));
        acc.x = fmaf(ww, v.x, acc.x);
        acc.y = fmaf(ww, v.y, acc.y);
        acc.z = fmaf(ww, v.z, acc.z);
        acc.w = fmaf(ww, v.w, acc.w);
      }
      e += 64;
      if (e >= e1) break;
      const int c2 = min(64, e1 - e);   // rare: degree > 64
      pk = (lane < c2) ? csr_pk[e + lane] : 0u;
    }

    // combine half-waves, scale, store to LDS
    acc.x += __shfl_xor(acc.x, 32);
    acc.y += __shfl_xor(acc.y, 32);
    acc.z += __shfl_xor(acc.z, 32);
    acc.w += __shfl_xor(acc.w, 32);
    const float dn = dst_norm[gr];
    if (h == 0) {
      *reinterpret_cast<float4*>(&agg[r][l32 << 2]) =
          make_float4(acc.x * dn, acc.y * dn, acc.z * dn, acc.w * dn);
    }

    gr += 4;
    e0 = ne0;
    e1 = ne1;
    pk0 = npk;
  }
  __syncthreads();

  // ---- phase 2: out[64][128] = agg @ W (W direct from global, L2-hot) ----
  const int tc = tid & 31;
  const int tr = tid >> 5;
  const int c0 = tc << 2;
  const float4* Wv = reinterpret_cast<const float4*>(W);

  float4 acc8[8];
  #pragma unroll
  for (int i = 0; i < 8; ++i) acc8[i] = make_float4(0.f, 0.f, 0.f, 0.f);

  #pragma unroll 2
  for (int k = 0; k < DIM; k += 4) {
    float4 w4[4];
    #pragma unroll
    for (int j = 0; j < 4; ++j) w4[j] = Wv[(k + j) * 32 + tc];
    #pragma unroll
    for (int i = 0; i < 8; ++i) {
      const float4 a = *reinterpret_cast<const float4*>(&agg[tr * 8 + i][k]);
      const float av[4] = {a.x, a.y, a.z, a.w};
      #pragma unroll
      for (int j = 0; j < 4; ++j) {
        acc8[i].x = fmaf(av[j], w4[j].x, acc8[i].x);
        acc8[i].y = fmaf(av[j], w4[j].y, acc8[i].y);
        acc8[i].z = fmaf(av[j], w4[j].z, acc8[i].z);
        acc8[i].w = fmaf(av[j], w4[j].w, acc8[i].w);
      }
    }
  }

  // ---- epilogue: bias + activation + store ----
  const float4 bv = *reinterpret_cast<const float4*>(bias + c0);
  #pragma unroll
  for (int i = 0; i < 8; ++i) {
    float4 v = acc8[i];
    v.x += bv.x; v.y += bv.y; v.z += bv.z; v.w += bv.w;
    if (ACT == 0) {
      v.x = v.x > 0.f ? v.x : expm1f(v.x);
      v.y = v.y > 0.f ? v.y : expm1f(v.y);
      v.z = v.z > 0.f ? v.z : expm1f(v.z);
      v.w = v.w > 0.f ? v.w : expm1f(v.w);
    } else {
      float m = fmaxf(fmaxf(v.x, v.y), fmaxf(v.z, v.w));
      #pragma unroll
      for (int off = 16; off >= 1; off >>= 1) m = fmaxf(m, __shfl_xor(m, off));
      v.x = expf(v.x - m);
      v.y = expf(v.y - m);
      v.z = expf(v.z - m);
      v.w = expf(v.w - m);
      float s = v.x + v.y + v.z + v.w;
      #pragma unroll
      for (int off = 16; off >= 1; off >>= 1) s += __shfl_xor(s, off);
      const float inv = 1.0f / s;
      v.x *= inv; v.y *= inv; v.z *= inv; v.w *= inv;
    }
    *reinterpret_cast<float4*>(out + (size_t)(brow + tr * 8 + i) * DIM + c0) = v;
  }
}

// ---------------------------------------------------------------------------
extern "C" void kernel_launch(void* const* d_in, const int* in_sizes, int n_in,
                              void* d_out, int out_size, void* d_ws,
                              size_t ws_size, hipStream_t stream) {
  const float* x  = (const float*)d_in[0];
  const float* W1 = (const float*)d_in[1];
  const float* b1 = (const float*)d_in[2];
  const float* W2 = (const float*)d_in[3];
  const float* b2 = (const float*)d_in[4];
  const float* W3 = (const float*)d_in[5];
  const float* b3 = (const float*)d_in[6];
  const int* esrc = (const int*)d_in[7];
  const int* edst = (const int*)d_in[8];

  char* ws = (char*)d_ws;
  int* deg_src = (int*)ws;        ws += (size_t)N_NODES * 4;
  int* deg_dst = (int*)ws;        ws += (size_t)N_NODES * 4;
  int* row_off = (int*)ws;        ws += (size_t)(N_NODES + 32) * 4;
  int* cursor  = (int*)ws;        ws += (size_t)N_NODES * 4;
  float* dst_norm = (float*)ws;   ws += (size_t)N_NODES * 4;
  int* bsum = (int*)ws;           ws += 128 * 4;
  int* bpre = (int*)ws;           ws += 128 * 4;
  unsigned* csr_pk = (unsigned*)ws;  ws += (size_t)N_EDGES * 4;

  float* y1 = (float*)d_out;
  float* y2 = y1 + (size_t)N_NODES * DIM;
  float* y3 = y2 + (size_t)N_NODES * DIM;

  // deg_src & deg_dst contiguous: one memset
  hipMemsetAsync(deg_src, 0, (size_t)N_NODES * 2 * sizeof(int), stream);

  k_hist<<<(N_EDGES + 255) / 256, 256, 0, stream>>>(esrc, edst, deg_src, deg_dst);
  k_bsum<<<N_NODES / 1024, 256, 0, stream>>>(deg_dst, dst_norm, bsum);
  k_bscan<<<1, 128, 0, stream>>>(bsum, bpre);
  k_rowoff<<<N_NODES / 1024, 1024, 0, stream>>>(deg_dst, bpre, row_off, cursor);
  k_fill<<<(N_EDGES + 255) / 256, 256, 0, stream>>>(esrc, edst, deg_src, cursor,
                                                    csr_pk);

  k_layer<0><<<N_NODES / 64, 256, 0, stream>>>(x, W1, b1, row_off, csr_pk,
                                               dst_norm, y1);
  k_layer<0><<<N_NODES / 64, 256, 0, stream>>>(y1, W2, b2, row_off, csr_pk,
                                               dst_norm, y2);
  k_layer<1><<<N_NODES / 64, 256, 0, stream>>>(y2, W3, b3, row_off, csr_pk,
                                               dst_norm, y3);
}

// Round 4
// 607.340 us; speedup vs baseline: 2.3200x; 1.3329x over previous
//
#include <hip/hip_runtime.h>
#include <cstdint>
#include <cstddef>

#define N_NODES 102400
#define N_EDGES 1638400
#define DIM 128

// f32 -> bf16 (round-to-nearest-even), no __hip_bfloat16 dependency
__device__ __forceinline__ unsigned short f2bf(float x) {
  unsigned u = __float_as_uint(x);
  u += 0x7FFFu + ((u >> 16) & 1u);
  return (unsigned short)(u >> 16);
}
__device__ __forceinline__ float bf_lo(unsigned u) {
  return __int_as_float((int)(u << 16));
}
__device__ __forceinline__ float bf_hi(unsigned u) {
  return __int_as_float((int)(u & 0xFFFF0000u));
}

// ---------------------------------------------------------------------------
// degree histograms
// ---------------------------------------------------------------------------
__global__ void k_hist(const int* __restrict__ esrc, const int* __restrict__ edst,
                       int* __restrict__ deg_src, int* __restrict__ deg_dst) {
  const int i = blockIdx.x * blockDim.x + threadIdx.x;
  if (i < N_EDGES) {
    atomicAdd(&deg_src[esrc[i]], 1);
    atomicAdd(&deg_dst[edst[i]], 1);
  }
}

// ---------------------------------------------------------------------------
// 100 blocks x 256: dst_norm + per-1024-node block sums of deg_dst
// ---------------------------------------------------------------------------
__global__ void k_bsum(const int* __restrict__ deg_dst, float* __restrict__ dst_norm,
                       int* __restrict__ bsum) {
  __shared__ int ws[4];
  const int tid  = threadIdx.x;
  const int base = blockIdx.x * 1024;
  int s = 0;
  #pragma unroll
  for (int t = 0; t < 4; ++t) {
    const int i = base + t * 256 + tid;
    const int d = deg_dst[i];
    s += d;
    dst_norm[i] = rsqrtf((float)(d > 0 ? d : 1));
  }
  #pragma unroll
  for (int off = 32; off >= 1; off >>= 1) s += __shfl_down(s, off);
  if ((tid & 63) == 0) ws[tid >> 6] = s;
  __syncthreads();
  if (tid == 0) bsum[blockIdx.x] = ws[0] + ws[1] + ws[2] + ws[3];
}

// ---------------------------------------------------------------------------
// 1 block x 128: exclusive scan of the 100 block sums
// ---------------------------------------------------------------------------
__global__ void k_bscan(const int* __restrict__ bsum, int* __restrict__ bpre) {
  const int tid = threadIdx.x;
  const int v = (tid < 100) ? bsum[tid] : 0;
  int s = v;
  #pragma unroll
  for (int off = 1; off < 64; off <<= 1) {
    const int t = __shfl_up(s, off);
    if ((tid & 63) >= off) s += t;
  }
  __shared__ int w0;
  if (tid == 63) w0 = s;
  __syncthreads();
  if (tid >= 64) s += w0;
  if (tid < 100) bpre[tid] = s - v;
}

// ---------------------------------------------------------------------------
// 100 blocks x 1024: block-local exclusive scan of deg_dst + bpre offset
// ---------------------------------------------------------------------------
__global__ void k_rowoff(const int* __restrict__ deg_dst, const int* __restrict__ bpre,
                         int* __restrict__ row_off, int* __restrict__ cursor) {
  __shared__ int wsum[16];
  const int tid  = threadIdx.x;
  const int lane = tid & 63;
  const int wid  = tid >> 6;
  const int i = blockIdx.x * 1024 + tid;
  const int d = deg_dst[i];
  int v = d;
  #pragma unroll
  for (int off = 1; off < 64; off <<= 1) {
    const int t = __shfl_up(v, off);
    if (lane >= off) v += t;
  }
  if (lane == 63) wsum[wid] = v;
  __syncthreads();
  if (tid < 16) {
    int w = wsum[tid];
    #pragma unroll
    for (int off = 1; off < 16; off <<= 1) {
      const int t = __shfl_up(w, off);
      if (tid >= off) w += t;
    }
    wsum[tid] = w;
  }
  __syncthreads();
  const int excl = bpre[blockIdx.x] + (wid > 0 ? wsum[wid - 1] : 0) + v - d;
  row_off[i] = excl;
  cursor[i]  = excl;
  if (i == N_NODES - 1) row_off[N_NODES] = excl + d;
}

// ---------------------------------------------------------------------------
// CSR fill, packed: (src-row byte offset) | min(deg_src,63) << 26
// shift = 8 for bf16 rows (256 B), 9 for f32 rows (512 B)
// ---------------------------------------------------------------------------
__global__ void k_fill(const int* __restrict__ esrc, const int* __restrict__ edst,
                       const int* __restrict__ deg_src, int* __restrict__ cursor,
                       unsigned* __restrict__ csr_pk, int shift) {
  const int i = blockIdx.x * blockDim.x + threadIdx.x;
  if (i < N_EDGES) {
    const int s  = esrc[i];
    const int dg = deg_src[s];
    const int pos = atomicAdd(&cursor[edst[i]], 1);
    csr_pk[pos] = ((unsigned)s << shift) | ((unsigned)(dg > 63 ? 63 : dg) << 26);
  }
}

// ---------------------------------------------------------------------------
// f32 -> bf16 row table conversion (4 elems/thread)
// ---------------------------------------------------------------------------
__global__ void k_cvt(const float* __restrict__ in, unsigned short* __restrict__ out) {
  const int i = blockIdx.x * blockDim.x + threadIdx.x;
  const float4 v = reinterpret_cast<const float4*>(in)[i];
  ushort4 o;
  o.x = f2bf(v.x);
  o.y = f2bf(v.y);
  o.z = f2bf(v.z);
  o.w = f2bf(v.w);
  reinterpret_cast<ushort4*>(out)[i] = o;
}

// ---------------------------------------------------------------------------
// Fused GCN layer. 32-row tile. Gather: BF=1 -> bf16 rows, quarter-wave per
// edge (4 edges/instr); BF=0 -> f32 rows, half-wave per edge. Then f32 GEMM
// (W direct from global, L2-hot), bias + activation, store; ELU layers also
// emit a bf16 copy of the output for the next layer's gather.
// ACT: 0 = ELU, 1 = row softmax
// ---------------------------------------------------------------------------
template <int ACT, int BF>
__global__ __launch_bounds__(256, 8) void k_layer(
    const void* __restrict__ featv, const float* __restrict__ W,
    const float* __restrict__ bias, const int* __restrict__ row_off,
    const unsigned* __restrict__ csr_pk, const float* __restrict__ dst_norm,
    float* __restrict__ out, unsigned short* __restrict__ fbn) {
  __shared__ float agg[32][132];

  const int tid  = threadIdx.x;
  const int lane = tid & 63;
  const int wid  = tid >> 6;
  const int brow = blockIdx.x * 32;
  const char* fbase = reinterpret_cast<const char*>(featv);

  // ---- phase 1: aggregation, 8 rows per wave ----
  for (int r = wid; r < 32; r += 4) {
    const int gr = brow + r;
    const int e0 = row_off[gr];
    const int e1 = row_off[gr + 1];
    float acc[8];
    #pragma unroll
    for (int i = 0; i < 8; ++i) acc[i] = 0.f;

    for (int e = e0; e < e1; e += 64) {
      const int cnt = min(64, e1 - e);
      const unsigned pk = (lane < cnt) ? csr_pk[e + lane] : 0u;
      const float wgt = (lane < cnt) ? rsqrtf((float)(pk >> 26)) : 0.f;
      const int off = (int)(pk & 0x03FFFFFFu);

      if (BF) {
        const int q  = lane >> 4;
        const int li = lane & 15;
        const int nq = (cnt + 3) >> 2;
        #pragma unroll 8
        for (int j = 0; j < nq; ++j) {
          const int srcl = 4 * j + q;
          const int o    = __shfl(off, srcl);
          const float ww = __shfl(wgt, srcl);
          const uint4 d = *reinterpret_cast<const uint4*>(
              fbase + (size_t)(unsigned)o + (li << 4));
          acc[0] = fmaf(ww, bf_lo(d.x), acc[0]);
          acc[1] = fmaf(ww, bf_hi(d.x), acc[1]);
          acc[2] = fmaf(ww, bf_lo(d.y), acc[2]);
          acc[3] = fmaf(ww, bf_hi(d.y), acc[3]);
          acc[4] = fmaf(ww, bf_lo(d.z), acc[4]);
          acc[5] = fmaf(ww, bf_hi(d.z), acc[5]);
          acc[6] = fmaf(ww, bf_lo(d.w), acc[6]);
          acc[7] = fmaf(ww, bf_hi(d.w), acc[7]);
        }
      } else {
        const int q  = lane >> 5;
        const int li = lane & 31;
        const int np = (cnt + 1) >> 1;
        #pragma unroll 8
        for (int j = 0; j < np; ++j) {
          const int srcl = 2 * j + q;
          const int o    = __shfl(off, srcl);
          const float ww = __shfl(wgt, srcl);
          const float4 v = *reinterpret_cast<const float4*>(
              fbase + (size_t)(unsigned)o + (li << 4));
          acc[0] = fmaf(ww, v.x, acc[0]);
          acc[1] = fmaf(ww, v.y, acc[1]);
          acc[2] = fmaf(ww, v.z, acc[2]);
          acc[3] = fmaf(ww, v.w, acc[3]);
        }
      }
    }

    const float dn = dst_norm[gr];
    if (BF) {
      #pragma unroll
      for (int i = 0; i < 8; ++i) {
        acc[i] += __shfl_xor(acc[i], 32);
        acc[i] += __shfl_xor(acc[i], 16);
        acc[i] *= dn;
      }
      if ((lane >> 4) == 0) {
        const int li = lane & 15;
        *reinterpret_cast<float4*>(&agg[r][li * 8]) =
            make_float4(acc[0], acc[1], acc[2], acc[3]);
        *reinterpret_cast<float4*>(&agg[r][li * 8 + 4]) =
            make_float4(acc[4], acc[5], acc[6], acc[7]);
      }
    } else {
      #pragma unroll
      for (int i = 0; i < 4; ++i) {
        acc[i] += __shfl_xor(acc[i], 32);
        acc[i] *= dn;
      }
      if ((lane >> 5) == 0) {
        const int li = lane & 31;
        *reinterpret_cast<float4*>(&agg[r][li * 4]) =
            make_float4(acc[0], acc[1], acc[2], acc[3]);
      }
    }
  }
  __syncthreads();

  // ---- phase 2: out[32][128] = agg @ W (W direct from global, L2-hot) ----
  const int tc = tid & 31;
  const int tr = tid >> 5;
  const int c0 = tc << 2;
  const float4* Wv = reinterpret_cast<const float4*>(W);

  float4 a4[4];
  #pragma unroll
  for (int i = 0; i < 4; ++i) a4[i] = make_float4(0.f, 0.f, 0.f, 0.f);

  #pragma unroll 2
  for (int k = 0; k < DIM; k += 4) {
    float4 w4[4];
    #pragma unroll
    for (int j = 0; j < 4; ++j) w4[j] = Wv[(k + j) * 32 + tc];
    #pragma unroll
    for (int i = 0; i < 4; ++i) {
      const float4 a = *reinterpret_cast<const float4*>(&agg[tr * 4 + i][k]);
      const float av[4] = {a.x, a.y, a.z, a.w};
      #pragma unroll
      for (int j = 0; j < 4; ++j) {
        a4[i].x = fmaf(av[j], w4[j].x, a4[i].x);
        a4[i].y = fmaf(av[j], w4[j].y, a4[i].y);
        a4[i].z = fmaf(av[j], w4[j].z, a4[i].z);
        a4[i].w = fmaf(av[j], w4[j].w, a4[i].w);
      }
    }
  }

  // ---- epilogue: bias + activation + store (+ bf16 copy for next layer) ----
  const float4 bv = *reinterpret_cast<const float4*>(bias + c0);
  #pragma unroll
  for (int i = 0; i < 4; ++i) {
    float4 v = a4[i];
    v.x += bv.x; v.y += bv.y; v.z += bv.z; v.w += bv.w;
    if (ACT == 0) {
      v.x = v.x > 0.f ? v.x : expm1f(v.x);
      v.y = v.y > 0.f ? v.y : expm1f(v.y);
      v.z = v.z > 0.f ? v.z : expm1f(v.z);
      v.w = v.w > 0.f ? v.w : expm1f(v.w);
    } else {
      float m = fmaxf(fmaxf(v.x, v.y), fmaxf(v.z, v.w));
      #pragma unroll
      for (int off = 16; off >= 1; off >>= 1) m = fmaxf(m, __shfl_xor(m, off));
      v.x = expf(v.x - m);
      v.y = expf(v.y - m);
      v.z = expf(v.z - m);
      v.w = expf(v.w - m);
      float s = v.x + v.y + v.z + v.w;
      #pragma unroll
      for (int off = 16; off >= 1; off >>= 1) s += __shfl_xor(s, off);
      const float inv = 1.0f / s;
      v.x *= inv; v.y *= inv; v.z *= inv; v.w *= inv;
    }
    const size_t row = (size_t)(brow + tr * 4 + i);
    *reinterpret_cast<float4*>(out + row * DIM + c0) = v;
    if (ACT == 0 && fbn != nullptr) {
      ushort4 o;
      o.x = f2bf(v.x);
      o.y = f2bf(v.y);
      o.z = f2bf(v.z);
      o.w = f2bf(v.w);
      *reinterpret_cast<ushort4*>(fbn + row * DIM + c0) = o;
    }
  }
}

// ---------------------------------------------------------------------------
extern "C" void kernel_launch(void* const* d_in, const int* in_sizes, int n_in,
                              void* d_out, int out_size, void* d_ws,
                              size_t ws_size, hipStream_t stream) {
  const float* x  = (const float*)d_in[0];
  const float* W1 = (const float*)d_in[1];
  const float* b1 = (const float*)d_in[2];
  const float* W2 = (const float*)d_in[3];
  const float* b2 = (const float*)d_in[4];
  const float* W3 = (const float*)d_in[5];
  const float* b3 = (const float*)d_in[6];
  const int* esrc = (const int*)d_in[7];
  const int* edst = (const int*)d_in[8];

  char* ws = (char*)d_ws;
  int* deg_src = (int*)ws;        ws += (size_t)N_NODES * 4;
  int* deg_dst = (int*)ws;        ws += (size_t)N_NODES * 4;
  int* row_off = (int*)ws;        ws += (size_t)(N_NODES + 32) * 4;
  int* cursor  = (int*)ws;        ws += (size_t)N_NODES * 4;
  float* dst_norm = (float*)ws;   ws += (size_t)N_NODES * 4;
  int* bsum = (int*)ws;           ws += 128 * 4;
  int* bpre = (int*)ws;           ws += 128 * 4;
  unsigned* csr_pk = (unsigned*)ws;  ws += (size_t)N_EDGES * 4;

  const size_t fb_bytes = (size_t)N_NODES * DIM * 2;  // 26.2 MB
  const size_t prep_bytes = (size_t)(ws - (char*)d_ws);
  const bool use_bf = ws_size >= prep_bytes + 2 * fb_bytes;

  unsigned short* fbA = (unsigned short*)ws;              // xb, reused as fb2
  unsigned short* fbB = (unsigned short*)(ws + fb_bytes); // fb1

  float* y1 = (float*)d_out;
  float* y2 = y1 + (size_t)N_NODES * DIM;
  float* y3 = y2 + (size_t)N_NODES * DIM;

  (void)hipMemsetAsync(deg_src, 0, (size_t)N_NODES * 2 * sizeof(int), stream);

  k_hist<<<(N_EDGES + 255) / 256, 256, 0, stream>>>(esrc, edst, deg_src, deg_dst);
  k_bsum<<<N_NODES / 1024, 256, 0, stream>>>(deg_dst, dst_norm, bsum);
  k_bscan<<<1, 128, 0, stream>>>(bsum, bpre);
  k_rowoff<<<N_NODES / 1024, 1024, 0, stream>>>(deg_dst, bpre, row_off, cursor);
  k_fill<<<(N_EDGES + 255) / 256, 256, 0, stream>>>(esrc, edst, deg_src, cursor,
                                                    csr_pk, use_bf ? 8 : 9);

  if (use_bf) {
    k_cvt<<<(N_NODES * DIM / 4 + 255) / 256, 256, 0, stream>>>(x, fbA);
    // L1: gather xb -> y1 (+ bf16 fb1)
    k_layer<0, 1><<<N_NODES / 32, 256, 0, stream>>>(
        fbA, W1, b1, row_off, csr_pk, dst_norm, y1, fbB);
    // L2: gather fb1 -> y2 (+ bf16 fb2, reusing fbA)
    k_layer<0, 1><<<N_NODES / 32, 256, 0, stream>>>(
        fbB, W2, b2, row_off, csr_pk, dst_norm, y2, fbA);
    // L3: gather fb2 -> y3 (softmax)
    k_layer<1, 1><<<N_NODES / 32, 256, 0, stream>>>(
        fbA, W3, b3, row_off, csr_pk, dst_norm, y3, nullptr);
  } else {
    k_layer<0, 0><<<N_NODES / 32, 256, 0, stream>>>(
        x, W1, b1, row_off, csr_pk, dst_norm, y1, nullptr);
    k_layer<0, 0><<<N_NODES / 32, 256, 0, stream>>>(
        y1, W2, b2, row_off, csr_pk, dst_norm, y2, nullptr);
    k_layer<1, 0><<<N_NODES / 32, 256, 0, stream>>>(
        y2, W3, b3, row_off, csr_pk, dst_norm, y3, nullptr);
  }
}

// Round 5
// 595.232 us; speedup vs baseline: 2.3672x; 1.0203x over previous
//
#include <hip/hip_runtime.h>
#include <cstdint>
#include <cstddef>

#define N_NODES 102400
#define N_EDGES 1638400
#define DIM 128

// f32 -> bf16 (round-to-nearest-even), no __hip_bfloat16 dependency
__device__ __forceinline__ unsigned short f2bf(float x) {
  unsigned u = __float_as_uint(x);
  u += 0x7FFFu + ((u >> 16) & 1u);
  return (unsigned short)(u >> 16);
}
__device__ __forceinline__ float bf_lo(unsigned u) {
  return __int_as_float((int)(u << 16));
}
__device__ __forceinline__ float bf_hi(unsigned u) {
  return __int_as_float((int)(u & 0xFFFF0000u));
}

// ---------------------------------------------------------------------------
// degree histograms
// ---------------------------------------------------------------------------
__global__ void k_hist(const int* __restrict__ esrc, const int* __restrict__ edst,
                       int* __restrict__ deg_src, int* __restrict__ deg_dst) {
  const int i = blockIdx.x * blockDim.x + threadIdx.x;
  if (i < N_EDGES) {
    atomicAdd(&deg_src[esrc[i]], 1);
    atomicAdd(&deg_dst[edst[i]], 1);
  }
}

// ---------------------------------------------------------------------------
// 100 blocks x 256: dst_norm + per-1024-node block sums of deg_dst
// ---------------------------------------------------------------------------
__global__ void k_bsum(const int* __restrict__ deg_dst, float* __restrict__ dst_norm,
                       int* __restrict__ bsum) {
  __shared__ int ws[4];
  const int tid  = threadIdx.x;
  const int base = blockIdx.x * 1024;
  int s = 0;
  #pragma unroll
  for (int t = 0; t < 4; ++t) {
    const int i = base + t * 256 + tid;
    const int d = deg_dst[i];
    s += d;
    dst_norm[i] = rsqrtf((float)(d > 0 ? d : 1));
  }
  #pragma unroll
  for (int off = 32; off >= 1; off >>= 1) s += __shfl_down(s, off);
  if ((tid & 63) == 0) ws[tid >> 6] = s;
  __syncthreads();
  if (tid == 0) bsum[blockIdx.x] = ws[0] + ws[1] + ws[2] + ws[3];
}

// ---------------------------------------------------------------------------
// 1 block x 128: exclusive scan of the 100 block sums
// ---------------------------------------------------------------------------
__global__ void k_bscan(const int* __restrict__ bsum, int* __restrict__ bpre) {
  const int tid = threadIdx.x;
  const int v = (tid < 100) ? bsum[tid] : 0;
  int s = v;
  #pragma unroll
  for (int off = 1; off < 64; off <<= 1) {
    const int t = __shfl_up(s, off);
    if ((tid & 63) >= off) s += t;
  }
  __shared__ int w0;
  if (tid == 63) w0 = s;
  __syncthreads();
  if (tid >= 64) s += w0;
  if (tid < 100) bpre[tid] = s - v;
}

// ---------------------------------------------------------------------------
// 100 blocks x 1024: block-local exclusive scan of deg_dst + bpre offset
// ---------------------------------------------------------------------------
__global__ void k_rowoff(const int* __restrict__ deg_dst, const int* __restrict__ bpre,
                         int* __restrict__ row_off, int* __restrict__ cursor) {
  __shared__ int wsum[16];
  const int tid  = threadIdx.x;
  const int lane = tid & 63;
  const int wid  = tid >> 6;
  const int i = blockIdx.x * 1024 + tid;
  const int d = deg_dst[i];
  int v = d;
  #pragma unroll
  for (int off = 1; off < 64; off <<= 1) {
    const int t = __shfl_up(v, off);
    if (lane >= off) v += t;
  }
  if (lane == 63) wsum[wid] = v;
  __syncthreads();
  if (tid < 16) {
    int w = wsum[tid];
    #pragma unroll
    for (int off = 1; off < 16; off <<= 1) {
      const int t = __shfl_up(w, off);
      if (tid >= off) w += t;
    }
    wsum[tid] = w;
  }
  __syncthreads();
  const int excl = bpre[blockIdx.x] + (wid > 0 ? wsum[wid - 1] : 0) + v - d;
  row_off[i] = excl;
  cursor[i]  = excl;
  if (i == N_NODES - 1) row_off[N_NODES] = excl + d;
}

// ---------------------------------------------------------------------------
// CSR fill, packed: (src-row byte offset) | min(deg_src,63) << 26
// shift = 8 for bf16 rows (256 B), 9 for f32 rows (512 B)
// ---------------------------------------------------------------------------
__global__ void k_fill(const int* __restrict__ esrc, const int* __restrict__ edst,
                       const int* __restrict__ deg_src, int* __restrict__ cursor,
                       unsigned* __restrict__ csr_pk, int shift) {
  const int i = blockIdx.x * blockDim.x + threadIdx.x;
  if (i < N_EDGES) {
    const int s  = esrc[i];
    const int dg = deg_src[s];
    const int pos = atomicAdd(&cursor[edst[i]], 1);
    csr_pk[pos] = ((unsigned)s << shift) | ((unsigned)(dg > 63 ? 63 : dg) << 26);
  }
}

// ---------------------------------------------------------------------------
// f32 -> bf16 row table conversion (4 elems/thread)
// ---------------------------------------------------------------------------
__global__ void k_cvt(const float* __restrict__ in, unsigned short* __restrict__ out) {
  const int i = blockIdx.x * blockDim.x + threadIdx.x;
  const float4 v = reinterpret_cast<const float4*>(in)[i];
  ushort4 o;
  o.x = f2bf(v.x);
  o.y = f2bf(v.y);
  o.z = f2bf(v.z);
  o.w = f2bf(v.w);
  reinterpret_cast<ushort4*>(out)[i] = o;
}

// ---------------------------------------------------------------------------
// Fused GCN layer. 32-row tile. Gather: BF=1 -> bf16 rows, quarter-wave per
// edge (4 edges/instr); BF=0 -> f32 rows, half-wave per edge. Then f32 GEMM
// (W direct from global, L2-hot), bias + activation, store; ELU layers also
// emit a bf16 copy of the output for the next layer's gather.
// ACT: 0 = ELU, 1 = row softmax
// ---------------------------------------------------------------------------
template <int ACT, int BF>
__global__ __launch_bounds__(256, 8) void k_layer(
    const void* __restrict__ featv, const float* __restrict__ W,
    const float* __restrict__ bias, const int* __restrict__ row_off,
    const unsigned* __restrict__ csr_pk, const float* __restrict__ dst_norm,
    float* __restrict__ out, unsigned short* __restrict__ fbn) {
  __shared__ float agg[32][132];

  const int tid  = threadIdx.x;
  const int lane = tid & 63;
  const int wid  = tid >> 6;
  const int brow = blockIdx.x * 32;
  const char* fbase = reinterpret_cast<const char*>(featv);

  // ---- phase 1: aggregation, 8 rows per wave ----
  for (int r = wid; r < 32; r += 4) {
    const int gr = brow + r;
    const int e0 = row_off[gr];
    const int e1 = row_off[gr + 1];
    float acc[8];
    #pragma unroll
    for (int i = 0; i < 8; ++i) acc[i] = 0.f;

    for (int e = e0; e < e1; e += 64) {
      const int cnt = min(64, e1 - e);
      const unsigned pk = (lane < cnt) ? csr_pk[e + lane] : 0u;
      const float wgt = (lane < cnt) ? rsqrtf((float)(pk >> 26)) : 0.f;
      const int off = (int)(pk & 0x03FFFFFFu);

      if (BF) {
        const int q  = lane >> 4;
        const int li = lane & 15;
        const int nq = (cnt + 3) >> 2;
        #pragma unroll 8
        for (int j = 0; j < nq; ++j) {
          const int srcl = 4 * j + q;
          const int o    = __shfl(off, srcl);
          const float ww = __shfl(wgt, srcl);
          const uint4 d = *reinterpret_cast<const uint4*>(
              fbase + (size_t)(unsigned)o + (li << 4));
          acc[0] = fmaf(ww, bf_lo(d.x), acc[0]);
          acc[1] = fmaf(ww, bf_hi(d.x), acc[1]);
          acc[2] = fmaf(ww, bf_lo(d.y), acc[2]);
          acc[3] = fmaf(ww, bf_hi(d.y), acc[3]);
          acc[4] = fmaf(ww, bf_lo(d.z), acc[4]);
          acc[5] = fmaf(ww, bf_hi(d.z), acc[5]);
          acc[6] = fmaf(ww, bf_lo(d.w), acc[6]);
          acc[7] = fmaf(ww, bf_hi(d.w), acc[7]);
        }
      } else {
        const int q  = lane >> 5;
        const int li = lane & 31;
        const int np = (cnt + 1) >> 1;
        #pragma unroll 8
        for (int j = 0; j < np; ++j) {
          const int srcl = 2 * j + q;
          const int o    = __shfl(off, srcl);
          const float ww = __shfl(wgt, srcl);
          const float4 v = *reinterpret_cast<const float4*>(
              fbase + (size_t)(unsigned)o + (li << 4));
          acc[0] = fmaf(ww, v.x, acc[0]);
          acc[1] = fmaf(ww, v.y, acc[1]);
          acc[2] = fmaf(ww, v.z, acc[2]);
          acc[3] = fmaf(ww, v.w, acc[3]);
        }
      }
    }

    const float dn = dst_norm[gr];
    if (BF) {
      #pragma unroll
      for (int i = 0; i < 8; ++i) {
        acc[i] += __shfl_xor(acc[i], 32);
        acc[i] += __shfl_xor(acc[i], 16);
        acc[i] *= dn;
      }
      if ((lane >> 4) == 0) {
        const int li = lane & 15;
        *reinterpret_cast<float4*>(&agg[r][li * 8]) =
            make_float4(acc[0], acc[1], acc[2], acc[3]);
        *reinterpret_cast<float4*>(&agg[r][li * 8 + 4]) =
            make_float4(acc[4], acc[5], acc[6], acc[7]);
      }
    } else {
      #pragma unroll
      for (int i = 0; i < 4; ++i) {
        acc[i] += __shfl_xor(acc[i], 32);
        acc[i] *= dn;
      }
      if ((lane >> 5) == 0) {
        const int li = lane & 31;
        *reinterpret_cast<float4*>(&agg[r][li * 4]) =
            make_float4(acc[0], acc[1], acc[2], acc[3]);
      }
    }
  }
  __syncthreads();

  // ---- phase 2: out[32][128] = agg @ W (W direct from global, L2-hot) ----
  const int tc = tid & 31;
  const int tr = tid >> 5;
  const int c0 = tc << 2;
  const float4* Wv = reinterpret_cast<const float4*>(W);

  float4 a4[4];
  #pragma unroll
  for (int i = 0; i < 4; ++i) a4[i] = make_float4(0.f, 0.f, 0.f, 0.f);

  #pragma unroll 2
  for (int k = 0; k < DIM; k += 4) {
    float4 w4[4];
    #pragma unroll
    for (int j = 0; j < 4; ++j) w4[j] = Wv[(k + j) * 32 + tc];
    #pragma unroll
    for (int i = 0; i < 4; ++i) {
      const float4 a = *reinterpret_cast<const float4*>(&agg[tr * 4 + i][k]);
      const float av[4] = {a.x, a.y, a.z, a.w};
      #pragma unroll
      for (int j = 0; j < 4; ++j) {
        a4[i].x = fmaf(av[j], w4[j].x, a4[i].x);
        a4[i].y = fmaf(av[j], w4[j].y, a4[i].y);
        a4[i].z = fmaf(av[j], w4[j].z, a4[i].z);
        a4[i].w = fmaf(av[j], w4[j].w, a4[i].w);
      }
    }
  }

  // ---- epilogue: bias + activation + store (+ bf16 copy for next layer) ----
  const float4 bv = *reinterpret_cast<const float4*>(bias + c0);
  #pragma unroll
  for (int i = 0; i < 4; ++i) {
    float4 v = a4[i];
    v.x += bv.x; v.y += bv.y; v.z += bv.z; v.w += bv.w;
    if (ACT == 0) {
      v.x = v.x > 0.f ? v.x : expm1f(v.x);
      v.y = v.y > 0.f ? v.y : expm1f(v.y);
      v.z = v.z > 0.f ? v.z : expm1f(v.z);
      v.w = v.w > 0.f ? v.w : expm1f(v.w);
    } else {
      float m = fmaxf(fmaxf(v.x, v.y), fmaxf(v.z, v.w));
      #pragma unroll
      for (int off = 16; off >= 1; off >>= 1) m = fmaxf(m, __shfl_xor(m, off));
      v.x = expf(v.x - m);
      v.y = expf(v.y - m);
      v.z = expf(v.z - m);
      v.w = expf(v.w - m);
      float s = v.x + v.y + v.z + v.w;
      #pragma unroll
      for (int off = 16; off >= 1; off >>= 1) s += __shfl_xor(s, off);
      const float inv = 1.0f / s;
      v.x *= inv; v.y *= inv; v.z *= inv; v.w *= inv;
    }
    const size_t row = (size_t)(brow + tr * 4 + i);
    *reinterpret_cast<float4*>(out + row * DIM + c0) = v;
    if (ACT == 0 && fbn != nullptr) {
      ushort4 o;
      o.x = f2bf(v.x);
      o.y = f2bf(v.y);
      o.z = f2bf(v.z);
      o.w = f2bf(v.w);
      *reinterpret_cast<ushort4*>(fbn + row * DIM + c0) = o;
    }
  }
}

// ---------------------------------------------------------------------------
extern "C" void kernel_launch(void* const* d_in, const int* in_sizes, int n_in,
                              void* d_out, int out_size, void* d_ws,
                              size_t ws_size, hipStream_t stream) {
  const float* x  = (const float*)d_in[0];
  const float* W1 = (const float*)d_in[1];
  const float* b1 = (const float*)d_in[2];
  const float* W2 = (const float*)d_in[3];
  const float* b2 = (const float*)d_in[4];
  const float* W3 = (const float*)d_in[5];
  const float* b3 = (const float*)d_in[6];
  const int* esrc = (const int*)d_in[7];
  const int* edst = (const int*)d_in[8];

  char* ws = (char*)d_ws;
  int* deg_src = (int*)ws;        ws += (size_t)N_NODES * 4;
  int* deg_dst = (int*)ws;        ws += (size_t)N_NODES * 4;
  int* row_off = (int*)ws;        ws += (size_t)(N_NODES + 32) * 4;
  int* cursor  = (int*)ws;        ws += (size_t)N_NODES * 4;
  float* dst_norm = (float*)ws;   ws += (size_t)N_NODES * 4;
  int* bsum = (int*)ws;           ws += 128 * 4;
  int* bpre = (int*)ws;           ws += 128 * 4;
  unsigned* csr_pk = (unsigned*)ws;  ws += (size_t)N_EDGES * 4;

  const size_t fb_bytes = (size_t)N_NODES * DIM * 2;  // 26.2 MB
  const size_t prep_bytes = (size_t)(ws - (char*)d_ws);
  const bool use_bf = ws_size >= prep_bytes + 2 * fb_bytes;

  unsigned short* fbA = (unsigned short*)ws;              // xb, reused as fb2
  unsigned short* fbB = (unsigned short*)(ws + fb_bytes); // fb1

  float* y1 = (float*)d_out;
  float* y2 = y1 + (size_t)N_NODES * DIM;
  float* y3 = y2 + (size_t)N_NODES * DIM;

  (void)hipMemsetAsync(deg_src, 0, (size_t)N_NODES * 2 * sizeof(int), stream);

  k_hist<<<(N_EDGES + 255) / 256, 256, 0, stream>>>(esrc, edst, deg_src, deg_dst);
  k_bsum<<<N_NODES / 1024, 256, 0, stream>>>(deg_dst, dst_norm, bsum);
  k_bscan<<<1, 128, 0, stream>>>(bsum, bpre);
  k_rowoff<<<N_NODES / 1024, 1024, 0, stream>>>(deg_dst, bpre, row_off, cursor);
  k_fill<<<(N_EDGES + 255) / 256, 256, 0, stream>>>(esrc, edst, deg_src, cursor,
                                                    csr_pk, use_bf ? 8 : 9);

  if (use_bf) {
    k_cvt<<<(N_NODES * DIM / 4 + 255) / 256, 256, 0, stream>>>(x, fbA);
    // L1: gather xb -> y1 (+ bf16 fb1)
    k_layer<0, 1><<<N_NODES / 32, 256, 0, stream>>>(
        fbA, W1, b1, row_off, csr_pk, dst_norm, y1, fbB);
    // L2: gather fb1 -> y2 (+ bf16 fb2, reusing fbA)
    k_layer<0, 1><<<N_NODES / 32, 256, 0, stream>>>(
        fbB, W2, b2, row_off, csr_pk, dst_norm, y2, fbA);
    // L3: gather fb2 -> y3 (softmax)
    k_layer<1, 1><<<N_NODES / 32, 256, 0, stream>>>(
        fbA, W3, b3, row_off, csr_pk, dst_norm, y3, nullptr);
  } else {
    k_layer<0, 0><<<N_NODES / 32, 256, 0, stream>>>(
        x, W1, b1, row_off, csr_pk, dst_norm, y1, nullptr);
    k_layer<0, 0><<<N_NODES / 32, 256, 0, stream>>>(
        y1, W2, b2, row_off, csr_pk, dst_norm, y2, nullptr);
    k_layer<1, 0><<<N_NODES / 32, 256, 0, stream>>>(
        y2, W3, b3, row_off, csr_pk, dst_norm, y3, nullptr);
  }
}

// Round 6
// 520.819 us; speedup vs baseline: 2.7055x; 1.1429x over previous
//
#include <hip/hip_runtime.h>
#include <cstdint>
#include <cstddef>

#define N_NODES 102400
#define N_EDGES 1638400
#define DIM 128
#define SLOTS 48

// f32 -> bf16 (round-to-nearest-even)
__device__ __forceinline__ unsigned short f2bf(float x) {
  unsigned u = __float_as_uint(x);
  u += 0x7FFFu + ((u >> 16) & 1u);
  return (unsigned short)(u >> 16);
}
__device__ __forceinline__ float bf_lo(unsigned u) {
  return __int_as_float((int)(u << 16));
}
__device__ __forceinline__ float bf_hi(unsigned u) {
  return __int_as_float((int)(u & 0xFFFF0000u));
}

// ===========================================================================
// NEW PATH: padded-CSR build (one pass) + prescaled bf16 features
// ===========================================================================

// one pass over edges: src out-degree histogram + direct padded-CSR fill.
// cnt[] doubles as deg_dst.
__global__ void k_build(const int* __restrict__ esrc, const int* __restrict__ edst,
                        int* __restrict__ deg_src, int* __restrict__ cnt,
                        unsigned* __restrict__ csr) {
  const int i = blockIdx.x * blockDim.x + threadIdx.x;
  if (i < N_EDGES) {
    const int s = esrc[i];
    const int d = edst[i];
    atomicAdd(&deg_src[s], 1);
    const int pos = atomicAdd(&cnt[d], 1);
    csr[d * SLOTS + pos] = (unsigned)s << 8;  // byte offset into bf16 row table
  }
}

// fbA[i] = bf16(x[i] * src_norm[row]) ; 4 elems/thread
__global__ void k_cvt_scale(const float* __restrict__ x,
                            const int* __restrict__ deg_src,
                            unsigned short* __restrict__ out) {
  const int i = blockIdx.x * blockDim.x + threadIdx.x;
  const int row = i >> 5;  // 32 float4 per 128-col row
  const int dg = deg_src[row];
  const float sn = rsqrtf((float)(dg > 0 ? dg : 1));
  const float4 v = reinterpret_cast<const float4*>(x)[i];
  ushort4 o;
  o.x = f2bf(v.x * sn);
  o.y = f2bf(v.y * sn);
  o.z = f2bf(v.z * sn);
  o.w = f2bf(v.w * sn);
  reinterpret_cast<ushort4*>(out)[i] = o;
}

// Fused layer, padded-CSR + prescaled bf16 features.
// Gather: quarter-wave (16 lanes) per edge row, next-row prefetch, pure adds.
// Then f32 GEMM from LDS, bias+act, store; ELU layers emit bf16(out*src_norm).
template <int ACT>
__global__ __launch_bounds__(256, 8) void k_layer_n(
    const unsigned short* __restrict__ fb_in, const float* __restrict__ W,
    const float* __restrict__ bias, const int* __restrict__ cnt,
    const unsigned* __restrict__ csr, const int* __restrict__ deg_src,
    float* __restrict__ out, unsigned short* __restrict__ fb_out) {
  __shared__ float agg[32][132];

  const int tid  = threadIdx.x;
  const int lane = tid & 63;
  const int wid  = tid >> 6;
  const int q    = lane >> 4;   // quarter-wave id (edge mod 4)
  const int li   = lane & 15;   // 16 lanes x 16B = 256B bf16 row
  const int brow = blockIdx.x * 32;
  const char* fbase = reinterpret_cast<const char*>(fb_in);

  // ---- phase 1: aggregation, 8 rows per wave, prefetched ----
  int gr = brow + wid;
  int c_cur = cnt[gr];
  unsigned pk_cur = (lane < c_cur) ? csr[gr * SLOTS + lane] : 0u;

  for (int r = wid; r < 32; r += 4) {
    int c_nxt = 0;
    unsigned pk_nxt = 0u;
    if (r + 4 < 32) {
      c_nxt = cnt[gr + 4];
      if (lane < c_nxt) pk_nxt = csr[(gr + 4) * SLOTS + lane];
    }

    float acc[8];
    #pragma unroll
    for (int i = 0; i < 8; ++i) acc[i] = 0.f;

    const int nq = (c_cur + 3) >> 2;
    #pragma unroll 4
    for (int j = 0; j < nq; ++j) {
      const int srcl = 4 * j + q;
      const int o = __shfl((int)pk_cur, srcl);
      if (srcl < c_cur) {
        const uint4 d = *reinterpret_cast<const uint4*>(
            fbase + (size_t)(unsigned)o + (li << 4));
        acc[0] += bf_lo(d.x);
        acc[1] += bf_hi(d.x);
        acc[2] += bf_lo(d.y);
        acc[3] += bf_hi(d.y);
        acc[4] += bf_lo(d.z);
        acc[5] += bf_hi(d.z);
        acc[6] += bf_lo(d.w);
        acc[7] += bf_hi(d.w);
      }
    }

    const float dn = rsqrtf((float)(c_cur > 0 ? c_cur : 1));
    #pragma unroll
    for (int i = 0; i < 8; ++i) {
      acc[i] += __shfl_xor(acc[i], 32);
      acc[i] += __shfl_xor(acc[i], 16);
      acc[i] *= dn;
    }
    if (q == 0) {
      *reinterpret_cast<float4*>(&agg[r][li * 8]) =
          make_float4(acc[0], acc[1], acc[2], acc[3]);
      *reinterpret_cast<float4*>(&agg[r][li * 8 + 4]) =
          make_float4(acc[4], acc[5], acc[6], acc[7]);
    }

    gr += 4;
    c_cur = c_nxt;
    pk_cur = pk_nxt;
  }
  __syncthreads();

  // ---- phase 2: out[32][128] = agg @ W (W direct from global, L2-hot) ----
  const int tc = tid & 31;
  const int tr = tid >> 5;
  const int c0 = tc << 2;
  const float4* Wv = reinterpret_cast<const float4*>(W);

  float4 a4[4];
  #pragma unroll
  for (int i = 0; i < 4; ++i) a4[i] = make_float4(0.f, 0.f, 0.f, 0.f);

  #pragma unroll 2
  for (int k = 0; k < DIM; k += 4) {
    float4 w4[4];
    #pragma unroll
    for (int j = 0; j < 4; ++j) w4[j] = Wv[(k + j) * 32 + tc];
    #pragma unroll
    for (int i = 0; i < 4; ++i) {
      const float4 a = *reinterpret_cast<const float4*>(&agg[tr * 4 + i][k]);
      const float av[4] = {a.x, a.y, a.z, a.w};
      #pragma unroll
      for (int j = 0; j < 4; ++j) {
        a4[i].x = fmaf(av[j], w4[j].x, a4[i].x);
        a4[i].y = fmaf(av[j], w4[j].y, a4[i].y);
        a4[i].z = fmaf(av[j], w4[j].z, a4[i].z);
        a4[i].w = fmaf(av[j], w4[j].w, a4[i].w);
      }
    }
  }

  // ---- epilogue ----
  const float4 bv = *reinterpret_cast<const float4*>(bias + c0);
  #pragma unroll
  for (int i = 0; i < 4; ++i) {
    float4 v = a4[i];
    v.x += bv.x; v.y += bv.y; v.z += bv.z; v.w += bv.w;
    if (ACT == 0) {
      v.x = v.x > 0.f ? v.x : expm1f(v.x);
      v.y = v.y > 0.f ? v.y : expm1f(v.y);
      v.z = v.z > 0.f ? v.z : expm1f(v.z);
      v.w = v.w > 0.f ? v.w : expm1f(v.w);
    } else {
      float m = fmaxf(fmaxf(v.x, v.y), fmaxf(v.z, v.w));
      #pragma unroll
      for (int off = 16; off >= 1; off >>= 1) m = fmaxf(m, __shfl_xor(m, off));
      v.x = expf(v.x - m);
      v.y = expf(v.y - m);
      v.z = expf(v.z - m);
      v.w = expf(v.w - m);
      float s = v.x + v.y + v.z + v.w;
      #pragma unroll
      for (int off = 16; off >= 1; off >>= 1) s += __shfl_xor(s, off);
      const float inv = 1.0f / s;
      v.x *= inv; v.y *= inv; v.z *= inv; v.w *= inv;
    }
    const size_t row = (size_t)(brow + tr * 4 + i);
    *reinterpret_cast<float4*>(out + row * DIM + c0) = v;
    if (ACT == 0 && fb_out != nullptr) {
      const int dg = deg_src[row];
      const float sn = rsqrtf((float)(dg > 0 ? dg : 1));
      ushort4 o;
      o.x = f2bf(v.x * sn);
      o.y = f2bf(v.y * sn);
      o.z = f2bf(v.z * sn);
      o.w = f2bf(v.w * sn);
      *reinterpret_cast<ushort4*>(fb_out + row * DIM + c0) = o;
    }
  }
}

// ===========================================================================
// FALLBACK PATH (round-5, compact CSR) — used when ws_size is too small
// ===========================================================================
__global__ void k_hist(const int* __restrict__ esrc, const int* __restrict__ edst,
                       int* __restrict__ deg_src, int* __restrict__ deg_dst) {
  const int i = blockIdx.x * blockDim.x + threadIdx.x;
  if (i < N_EDGES) {
    atomicAdd(&deg_src[esrc[i]], 1);
    atomicAdd(&deg_dst[edst[i]], 1);
  }
}

__global__ void k_bsum(const int* __restrict__ deg_dst, float* __restrict__ dst_norm,
                       int* __restrict__ bsum) {
  __shared__ int ws[4];
  const int tid  = threadIdx.x;
  const int base = blockIdx.x * 1024;
  int s = 0;
  #pragma unroll
  for (int t = 0; t < 4; ++t) {
    const int i = base + t * 256 + tid;
    const int d = deg_dst[i];
    s += d;
    dst_norm[i] = rsqrtf((float)(d > 0 ? d : 1));
  }
  #pragma unroll
  for (int off = 32; off >= 1; off >>= 1) s += __shfl_down(s, off);
  if ((tid & 63) == 0) ws[tid >> 6] = s;
  __syncthreads();
  if (tid == 0) bsum[blockIdx.x] = ws[0] + ws[1] + ws[2] + ws[3];
}

__global__ void k_bscan(const int* __restrict__ bsum, int* __restrict__ bpre) {
  const int tid = threadIdx.x;
  const int v = (tid < 100) ? bsum[tid] : 0;
  int s = v;
  #pragma unroll
  for (int off = 1; off < 64; off <<= 1) {
    const int t = __shfl_up(s, off);
    if ((tid & 63) >= off) s += t;
  }
  __shared__ int w0;
  if (tid == 63) w0 = s;
  __syncthreads();
  if (tid >= 64) s += w0;
  if (tid < 100) bpre[tid] = s - v;
}

__global__ void k_rowoff(const int* __restrict__ deg_dst, const int* __restrict__ bpre,
                         int* __restrict__ row_off, int* __restrict__ cursor) {
  __shared__ int wsum[16];
  const int tid  = threadIdx.x;
  const int lane = tid & 63;
  const int wid  = tid >> 6;
  const int i = blockIdx.x * 1024 + tid;
  const int d = deg_dst[i];
  int v = d;
  #pragma unroll
  for (int off = 1; off < 64; off <<= 1) {
    const int t = __shfl_up(v, off);
    if (lane >= off) v += t;
  }
  if (lane == 63) wsum[wid] = v;
  __syncthreads();
  if (tid < 16) {
    int w = wsum[tid];
    #pragma unroll
    for (int off = 1; off < 16; off <<= 1) {
      const int t = __shfl_up(w, off);
      if (tid >= off) w += t;
    }
    wsum[tid] = w;
  }
  __syncthreads();
  const int excl = bpre[blockIdx.x] + (wid > 0 ? wsum[wid - 1] : 0) + v - d;
  row_off[i] = excl;
  cursor[i]  = excl;
  if (i == N_NODES - 1) row_off[N_NODES] = excl + d;
}

__global__ void k_fill(const int* __restrict__ esrc, const int* __restrict__ edst,
                       const int* __restrict__ deg_src, int* __restrict__ cursor,
                       unsigned* __restrict__ csr_pk, int shift) {
  const int i = blockIdx.x * blockDim.x + threadIdx.x;
  if (i < N_EDGES) {
    const int s  = esrc[i];
    const int dg = deg_src[s];
    const int pos = atomicAdd(&cursor[edst[i]], 1);
    csr_pk[pos] = ((unsigned)s << shift) | ((unsigned)(dg > 63 ? 63 : dg) << 26);
  }
}

__global__ void k_cvt(const float* __restrict__ in, unsigned short* __restrict__ out) {
  const int i = blockIdx.x * blockDim.x + threadIdx.x;
  const float4 v = reinterpret_cast<const float4*>(in)[i];
  ushort4 o;
  o.x = f2bf(v.x);
  o.y = f2bf(v.y);
  o.z = f2bf(v.z);
  o.w = f2bf(v.w);
  reinterpret_cast<ushort4*>(out)[i] = o;
}

template <int ACT, int BF>
__global__ __launch_bounds__(256, 8) void k_layer(
    const void* __restrict__ featv, const float* __restrict__ W,
    const float* __restrict__ bias, const int* __restrict__ row_off,
    const unsigned* __restrict__ csr_pk, const float* __restrict__ dst_norm,
    float* __restrict__ out, unsigned short* __restrict__ fbn) {
  __shared__ float agg[32][132];

  const int tid  = threadIdx.x;
  const int lane = tid & 63;
  const int wid  = tid >> 6;
  const int brow = blockIdx.x * 32;
  const char* fbase = reinterpret_cast<const char*>(featv);

  for (int r = wid; r < 32; r += 4) {
    const int gr = brow + r;
    const int e0 = row_off[gr];
    const int e1 = row_off[gr + 1];
    float acc[8];
    #pragma unroll
    for (int i = 0; i < 8; ++i) acc[i] = 0.f;

    for (int e = e0; e < e1; e += 64) {
      const int cnt = min(64, e1 - e);
      const unsigned pk = (lane < cnt) ? csr_pk[e + lane] : 0u;
      const float wgt = (lane < cnt) ? rsqrtf((float)(pk >> 26)) : 0.f;
      const int off = (int)(pk & 0x03FFFFFFu);

      if (BF) {
        const int q  = lane >> 4;
        const int li = lane & 15;
        const int nq = (cnt + 3) >> 2;
        #pragma unroll 8
        for (int j = 0; j < nq; ++j) {
          const int srcl = 4 * j + q;
          const int o    = __shfl(off, srcl);
          const float ww = __shfl(wgt, srcl);
          const uint4 d = *reinterpret_cast<const uint4*>(
              fbase + (size_t)(unsigned)o + (li << 4));
          acc[0] = fmaf(ww, bf_lo(d.x), acc[0]);
          acc[1] = fmaf(ww, bf_hi(d.x), acc[1]);
          acc[2] = fmaf(ww, bf_lo(d.y), acc[2]);
          acc[3] = fmaf(ww, bf_hi(d.y), acc[3]);
          acc[4] = fmaf(ww, bf_lo(d.z), acc[4]);
          acc[5] = fmaf(ww, bf_hi(d.z), acc[5]);
          acc[6] = fmaf(ww, bf_lo(d.w), acc[6]);
          acc[7] = fmaf(ww, bf_hi(d.w), acc[7]);
        }
      } else {
        const int q  = lane >> 5;
        const int li = lane & 31;
        const int np = (cnt + 1) >> 1;
        #pragma unroll 8
        for (int j = 0; j < np; ++j) {
          const int srcl = 2 * j + q;
          const int o    = __shfl(off, srcl);
          const float ww = __shfl(wgt, srcl);
          const float4 v = *reinterpret_cast<const float4*>(
              fbase + (size_t)(unsigned)o + (li << 4));
          acc[0] = fmaf(ww, v.x, acc[0]);
          acc[1] = fmaf(ww, v.y, acc[1]);
          acc[2] = fmaf(ww, v.z, acc[2]);
          acc[3] = fmaf(ww, v.w, acc[3]);
        }
      }
    }

    const float dn = dst_norm[gr];
    if (BF) {
      #pragma unroll
      for (int i = 0; i < 8; ++i) {
        acc[i] += __shfl_xor(acc[i], 32);
        acc[i] += __shfl_xor(acc[i], 16);
        acc[i] *= dn;
      }
      if ((lane >> 4) == 0) {
        const int li = lane & 15;
        *reinterpret_cast<float4*>(&agg[r][li * 8]) =
            make_float4(acc[0], acc[1], acc[2], acc[3]);
        *reinterpret_cast<float4*>(&agg[r][li * 8 + 4]) =
            make_float4(acc[4], acc[5], acc[6], acc[7]);
      }
    } else {
      #pragma unroll
      for (int i = 0; i < 4; ++i) {
        acc[i] += __shfl_xor(acc[i], 32);
        acc[i] *= dn;
      }
      if ((lane >> 5) == 0) {
        const int li = lane & 31;
        *reinterpret_cast<float4*>(&agg[r][li * 4]) =
            make_float4(acc[0], acc[1], acc[2], acc[3]);
      }
    }
  }
  __syncthreads();

  const int tc = tid & 31;
  const int tr = tid >> 5;
  const int c0 = tc << 2;
  const float4* Wv = reinterpret_cast<const float4*>(W);

  float4 a4[4];
  #pragma unroll
  for (int i = 0; i < 4; ++i) a4[i] = make_float4(0.f, 0.f, 0.f, 0.f);

  #pragma unroll 2
  for (int k = 0; k < DIM; k += 4) {
    float4 w4[4];
    #pragma unroll
    for (int j = 0; j < 4; ++j) w4[j] = Wv[(k + j) * 32 + tc];
    #pragma unroll
    for (int i = 0; i < 4; ++i) {
      const float4 a = *reinterpret_cast<const float4*>(&agg[tr * 4 + i][k]);
      const float av[4] = {a.x, a.y, a.z, a.w};
      #pragma unroll
      for (int j = 0; j < 4; ++j) {
        a4[i].x = fmaf(av[j], w4[j].x, a4[i].x);
        a4[i].y = fmaf(av[j], w4[j].y, a4[i].y);
        a4[i].z = fmaf(av[j], w4[j].z, a4[i].z);
        a4[i].w = fmaf(av[j], w4[j].w, a4[i].w);
      }
    }
  }

  const float4 bv = *reinterpret_cast<const float4*>(bias + c0);
  #pragma unroll
  for (int i = 0; i < 4; ++i) {
    float4 v = a4[i];
    v.x += bv.x; v.y += bv.y; v.z += bv.z; v.w += bv.w;
    if (ACT == 0) {
      v.x = v.x > 0.f ? v.x : expm1f(v.x);
      v.y = v.y > 0.f ? v.y : expm1f(v.y);
      v.z = v.z > 0.f ? v.z : expm1f(v.z);
      v.w = v.w > 0.f ? v.w : expm1f(v.w);
    } else {
      float m = fmaxf(fmaxf(v.x, v.y), fmaxf(v.z, v.w));
      #pragma unroll
      for (int off = 16; off >= 1; off >>= 1) m = fmaxf(m, __shfl_xor(m, off));
      v.x = expf(v.x - m);
      v.y = expf(v.y - m);
      v.z = expf(v.z - m);
      v.w = expf(v.w - m);
      float s = v.x + v.y + v.z + v.w;
      #pragma unroll
      for (int off = 16; off >= 1; off >>= 1) s += __shfl_xor(s, off);
      const float inv = 1.0f / s;
      v.x *= inv; v.y *= inv; v.z *= inv; v.w *= inv;
    }
    const size_t row = (size_t)(brow + tr * 4 + i);
    *reinterpret_cast<float4*>(out + row * DIM + c0) = v;
    if (ACT == 0 && fbn != nullptr) {
      ushort4 o;
      o.x = f2bf(v.x);
      o.y = f2bf(v.y);
      o.z = f2bf(v.z);
      o.w = f2bf(v.w);
      *reinterpret_cast<ushort4*>(fbn + row * DIM + c0) = o;
    }
  }
}

// ---------------------------------------------------------------------------
extern "C" void kernel_launch(void* const* d_in, const int* in_sizes, int n_in,
                              void* d_out, int out_size, void* d_ws,
                              size_t ws_size, hipStream_t stream) {
  const float* x  = (const float*)d_in[0];
  const float* W1 = (const float*)d_in[1];
  const float* b1 = (const float*)d_in[2];
  const float* W2 = (const float*)d_in[3];
  const float* b2 = (const float*)d_in[4];
  const float* W3 = (const float*)d_in[5];
  const float* b3 = (const float*)d_in[6];
  const int* esrc = (const int*)d_in[7];
  const int* edst = (const int*)d_in[8];

  float* y1 = (float*)d_out;
  float* y2 = y1 + (size_t)N_NODES * DIM;
  float* y3 = y2 + (size_t)N_NODES * DIM;

  const size_t fb_bytes = (size_t)N_NODES * DIM * 2;  // 26.2 MB

  // ---- new-path workspace layout ----
  const size_t need_new = (size_t)N_NODES * 4 * 2          // deg_src + cnt
                        + (size_t)N_NODES * SLOTS * 4      // padded CSR
                        + 2 * fb_bytes;                    // fbA + fbB
  if (ws_size >= need_new) {
    char* ws = (char*)d_ws;
    int* deg_src = (int*)ws;  ws += (size_t)N_NODES * 4;
    int* cnt     = (int*)ws;  ws += (size_t)N_NODES * 4;
    unsigned* csr = (unsigned*)ws;  ws += (size_t)N_NODES * SLOTS * 4;
    unsigned short* fbA = (unsigned short*)ws;  ws += fb_bytes;
    unsigned short* fbB = (unsigned short*)ws;

    (void)hipMemsetAsync(deg_src, 0, (size_t)N_NODES * 2 * sizeof(int), stream);
    k_build<<<(N_EDGES + 255) / 256, 256, 0, stream>>>(esrc, edst, deg_src, cnt,
                                                       csr);
    k_cvt_scale<<<N_NODES * DIM / 4 / 256, 256, 0, stream>>>(x, deg_src, fbA);

    k_layer_n<0><<<N_NODES / 32, 256, 0, stream>>>(
        fbA, W1, b1, cnt, csr, deg_src, y1, fbB);
    k_layer_n<0><<<N_NODES / 32, 256, 0, stream>>>(
        fbB, W2, b2, cnt, csr, deg_src, y2, fbA);
    k_layer_n<1><<<N_NODES / 32, 256, 0, stream>>>(
        fbA, W3, b3, cnt, csr, deg_src, y3, nullptr);
    return;
  }

  // ---- fallback: round-5 compact-CSR path ----
  char* ws = (char*)d_ws;
  int* deg_src = (int*)ws;        ws += (size_t)N_NODES * 4;
  int* deg_dst = (int*)ws;        ws += (size_t)N_NODES * 4;
  int* row_off = (int*)ws;        ws += (size_t)(N_NODES + 32) * 4;
  int* cursor  = (int*)ws;        ws += (size_t)N_NODES * 4;
  float* dst_norm = (float*)ws;   ws += (size_t)N_NODES * 4;
  int* bsum = (int*)ws;           ws += 128 * 4;
  int* bpre = (int*)ws;           ws += 128 * 4;
  unsigned* csr_pk = (unsigned*)ws;  ws += (size_t)N_EDGES * 4;

  const size_t prep_bytes = (size_t)(ws - (char*)d_ws);
  const bool use_bf = ws_size >= prep_bytes + 2 * fb_bytes;

  unsigned short* fbA = (unsigned short*)ws;
  unsigned short* fbB = (unsigned short*)(ws + fb_bytes);

  (void)hipMemsetAsync(deg_src, 0, (size_t)N_NODES * 2 * sizeof(int), stream);

  k_hist<<<(N_EDGES + 255) / 256, 256, 0, stream>>>(esrc, edst, deg_src, deg_dst);
  k_bsum<<<N_NODES / 1024, 256, 0, stream>>>(deg_dst, dst_norm, bsum);
  k_bscan<<<1, 128, 0, stream>>>(bsum, bpre);
  k_rowoff<<<N_NODES / 1024, 1024, 0, stream>>>(deg_dst, bpre, row_off, cursor);
  k_fill<<<(N_EDGES + 255) / 256, 256, 0, stream>>>(esrc, edst, deg_src, cursor,
                                                    csr_pk, use_bf ? 8 : 9);

  if (use_bf) {
    k_cvt<<<(N_NODES * DIM / 4 + 255) / 256, 256, 0, stream>>>(x, fbA);
    k_layer<0, 1><<<N_NODES / 32, 256, 0, stream>>>(
        fbA, W1, b1, row_off, csr_pk, dst_norm, y1, fbB);
    k_layer<0, 1><<<N_NODES / 32, 256, 0, stream>>>(
        fbB, W2, b2, row_off, csr_pk, dst_norm, y2, fbA);
    k_layer<1, 1><<<N_NODES / 32, 256, 0, stream>>>(
        fbA, W3, b3, row_off, csr_pk, dst_norm, y3, nullptr);
  } else {
    k_layer<0, 0><<<N_NODES / 32, 256, 0, stream>>>(
        x, W1, b1, row_off, csr_pk, dst_norm, y1, nullptr);
    k_layer<0, 0><<<N_NODES / 32, 256, 0, stream>>>(
        y1, W2, b2, row_off, csr_pk, dst_norm, y2, nullptr);
    k_layer<1, 0><<<N_NODES / 32, 256, 0, stream>>>(
        y2, W3, b3, row_off, csr_pk, dst_norm, y3, nullptr);
  }
}

// Round 7
// 423.288 us; speedup vs baseline: 3.3288x; 1.2304x over previous
//
#include <hip/hip_runtime.h>
#include <cstdint>
#include <cstddef>

#define N_NODES 102400
#define N_EDGES 1638400
#define DIM 128
#define SLOTS 48
#define NB 200          // buckets: node>>9, 512 nodes each (200*512 = 102400)
#define BKT_CAP 9216    // 8192 avg + 11 sigma
#define SC_BLOCKS 400   // 400 * 4096 = 1638400 edges
#define SC_EPT 16       // edges per thread (256 thr * 16 = 4096)

// f32 -> bf16 (round-to-nearest-even)
__device__ __forceinline__ unsigned short f2bf(float x) {
  unsigned u = __float_as_uint(x);
  u += 0x7FFFu + ((u >> 16) & 1u);
  return (unsigned short)(u >> 16);
}
__device__ __forceinline__ float bf_lo(unsigned u) {
  return __int_as_float((int)(u << 16));
}
__device__ __forceinline__ float bf_hi(unsigned u) {
  return __int_as_float((int)(u & 0xFFFF0000u));
}

// ===========================================================================
// V2 BUILD: bucket partition, LDS-atomic CSR fill (no per-edge global atomics)
// ===========================================================================

__global__ void k_initcur(int* __restrict__ dstCur, int* __restrict__ srcCur) {
  const int i = threadIdx.x;
  if (i < NB) {
    dstCur[i] = i * BKT_CAP;
    srcCur[i] = i * BKT_CAP;
  }
}

// Partition edges into 200 dst-buckets (packed (src<<9)|dstLocal) and
// 200 src-buckets (srcLocal as u16). One global atomic per block per bucket.
__global__ __launch_bounds__(256) void k_scatter(
    const int* __restrict__ esrc, const int* __restrict__ edst,
    int* __restrict__ dstCur, int* __restrict__ srcCur,
    unsigned* __restrict__ dstStage, unsigned short* __restrict__ srcStage) {
  __shared__ int histD[NB], histS[NB], baseD[NB], baseS[NB], locD[NB], locS[NB];
  const int tid = threadIdx.x;
  const int ebase = blockIdx.x * (256 * SC_EPT);

  for (int i = tid; i < NB; i += 256) {
    histD[i] = 0; histS[i] = 0; locD[i] = 0; locS[i] = 0;
  }
  __syncthreads();

  int s[SC_EPT], d[SC_EPT];
  #pragma unroll
  for (int k = 0; k < SC_EPT; ++k) {
    const int e = ebase + k * 256 + tid;
    s[k] = esrc[e];
    d[k] = edst[e];
    atomicAdd(&histD[d[k] >> 9], 1);
    atomicAdd(&histS[s[k] >> 9], 1);
  }
  __syncthreads();

  for (int i = tid; i < NB; i += 256) {
    baseD[i] = atomicAdd(&dstCur[i], histD[i]);
    baseS[i] = atomicAdd(&srcCur[i], histS[i]);
  }
  __syncthreads();

  #pragma unroll
  for (int k = 0; k < SC_EPT; ++k) {
    const int bd = d[k] >> 9;
    const int od = atomicAdd(&locD[bd], 1);
    dstStage[baseD[bd] + od] = ((unsigned)s[k] << 9) | (unsigned)(d[k] & 511);
    const int bs = s[k] >> 9;
    const int os = atomicAdd(&locS[bs], 1);
    srcStage[baseS[bs] + os] = (unsigned short)(s[k] & 511);
  }
}

// One block per dst-bucket: LDS count + LDS-cursor CSR fill (L2-local region).
__global__ __launch_bounds__(256) void k_csr(
    const unsigned* __restrict__ dstStage, const int* __restrict__ dstCur,
    int* __restrict__ cnt, unsigned* __restrict__ csr) {
  __shared__ int c[512], cur[512];
  const int b = blockIdx.x;
  const int tid = threadIdx.x;
  #pragma unroll
  for (int k = 0; k < 2; ++k) { c[tid + k * 256] = 0; cur[tid + k * 256] = 0; }
  __syncthreads();

  const int base = b * BKT_CAP;
  const int n = dstCur[b] - base;
  for (int i = tid; i < n; i += 256) {
    atomicAdd(&c[dstStage[base + i] & 511], 1);
  }
  __syncthreads();

  const int node0 = b * 512;
  #pragma unroll
  for (int k = 0; k < 2; ++k) cnt[node0 + tid + k * 256] = c[tid + k * 256];

  for (int i = tid; i < n; i += 256) {
    const unsigned e = dstStage[base + i];
    const int dloc = (int)(e & 511u);
    const int slot = atomicAdd(&cur[dloc], 1);
    csr[(size_t)(node0 + dloc) * SLOTS + slot] = (e >> 9) << 8;  // src byte off
  }
}

// One block per src-bucket: out-degree counts, coalesced write.
__global__ __launch_bounds__(256) void k_sdeg(
    const unsigned short* __restrict__ srcStage, const int* __restrict__ srcCur,
    int* __restrict__ deg_src) {
  __shared__ int c[512];
  const int b = blockIdx.x;
  const int tid = threadIdx.x;
  #pragma unroll
  for (int k = 0; k < 2; ++k) c[tid + k * 256] = 0;
  __syncthreads();
  const int base = b * BKT_CAP;
  const int n = srcCur[b] - base;
  for (int i = tid; i < n; i += 256) {
    atomicAdd(&c[srcStage[base + i]], 1);
  }
  __syncthreads();
  const int node0 = b * 512;
  #pragma unroll
  for (int k = 0; k < 2; ++k) deg_src[node0 + tid + k * 256] = c[tid + k * 256];
}

// fb[i] = bf16(x[i] * src_norm[row]) ; 4 elems/thread
__global__ void k_cvt_scale(const float* __restrict__ x,
                            const int* __restrict__ deg_src,
                            unsigned short* __restrict__ out) {
  const int i = blockIdx.x * blockDim.x + threadIdx.x;
  const int row = i >> 5;
  const int dg = deg_src[row];
  const float sn = rsqrtf((float)(dg > 0 ? dg : 1));
  const float4 v = reinterpret_cast<const float4*>(x)[i];
  ushort4 o;
  o.x = f2bf(v.x * sn);
  o.y = f2bf(v.y * sn);
  o.z = f2bf(v.z * sn);
  o.w = f2bf(v.w * sn);
  reinterpret_cast<ushort4*>(out)[i] = o;
}

// ---------------------------------------------------------------------------
// Fused layer (unchanged from round 6): padded-CSR, prescaled bf16 features.
// ---------------------------------------------------------------------------
template <int ACT>
__global__ __launch_bounds__(256, 8) void k_layer_n(
    const unsigned short* __restrict__ fb_in, const float* __restrict__ W,
    const float* __restrict__ bias, const int* __restrict__ cnt,
    const unsigned* __restrict__ csr, const int* __restrict__ deg_src,
    float* __restrict__ out, unsigned short* __restrict__ fb_out) {
  __shared__ float agg[32][132];

  const int tid  = threadIdx.x;
  const int lane = tid & 63;
  const int wid  = tid >> 6;
  const int q    = lane >> 4;
  const int li   = lane & 15;
  const int brow = blockIdx.x * 32;
  const char* fbase = reinterpret_cast<const char*>(fb_in);

  int gr = brow + wid;
  int c_cur = cnt[gr];
  unsigned pk_cur = (lane < c_cur) ? csr[(size_t)gr * SLOTS + lane] : 0u;

  for (int r = wid; r < 32; r += 4) {
    int c_nxt = 0;
    unsigned pk_nxt = 0u;
    if (r + 4 < 32) {
      c_nxt = cnt[gr + 4];
      if (lane < c_nxt) pk_nxt = csr[(size_t)(gr + 4) * SLOTS + lane];
    }

    float acc[8];
    #pragma unroll
    for (int i = 0; i < 8; ++i) acc[i] = 0.f;

    const int nq = (c_cur + 3) >> 2;
    #pragma unroll 4
    for (int j = 0; j < nq; ++j) {
      const int srcl = 4 * j + q;
      const int o = __shfl((int)pk_cur, srcl);
      if (srcl < c_cur) {
        const uint4 dd = *reinterpret_cast<const uint4*>(
            fbase + (size_t)(unsigned)o + (li << 4));
        acc[0] += bf_lo(dd.x);
        acc[1] += bf_hi(dd.x);
        acc[2] += bf_lo(dd.y);
        acc[3] += bf_hi(dd.y);
        acc[4] += bf_lo(dd.z);
        acc[5] += bf_hi(dd.z);
        acc[6] += bf_lo(dd.w);
        acc[7] += bf_hi(dd.w);
      }
    }

    const float dn = rsqrtf((float)(c_cur > 0 ? c_cur : 1));
    #pragma unroll
    for (int i = 0; i < 8; ++i) {
      acc[i] += __shfl_xor(acc[i], 32);
      acc[i] += __shfl_xor(acc[i], 16);
      acc[i] *= dn;
    }
    if (q == 0) {
      *reinterpret_cast<float4*>(&agg[r][li * 8]) =
          make_float4(acc[0], acc[1], acc[2], acc[3]);
      *reinterpret_cast<float4*>(&agg[r][li * 8 + 4]) =
          make_float4(acc[4], acc[5], acc[6], acc[7]);
    }

    gr += 4;
    c_cur = c_nxt;
    pk_cur = pk_nxt;
  }
  __syncthreads();

  const int tc = tid & 31;
  const int tr = tid >> 5;
  const int c0 = tc << 2;
  const float4* Wv = reinterpret_cast<const float4*>(W);

  float4 a4[4];
  #pragma unroll
  for (int i = 0; i < 4; ++i) a4[i] = make_float4(0.f, 0.f, 0.f, 0.f);

  #pragma unroll 2
  for (int k = 0; k < DIM; k += 4) {
    float4 w4[4];
    #pragma unroll
    for (int j = 0; j < 4; ++j) w4[j] = Wv[(k + j) * 32 + tc];
    #pragma unroll
    for (int i = 0; i < 4; ++i) {
      const float4 a = *reinterpret_cast<const float4*>(&agg[tr * 4 + i][k]);
      const float av[4] = {a.x, a.y, a.z, a.w};
      #pragma unroll
      for (int j = 0; j < 4; ++j) {
        a4[i].x = fmaf(av[j], w4[j].x, a4[i].x);
        a4[i].y = fmaf(av[j], w4[j].y, a4[i].y);
        a4[i].z = fmaf(av[j], w4[j].z, a4[i].z);
        a4[i].w = fmaf(av[j], w4[j].w, a4[i].w);
      }
    }
  }

  const float4 bv = *reinterpret_cast<const float4*>(bias + c0);
  #pragma unroll
  for (int i = 0; i < 4; ++i) {
    float4 v = a4[i];
    v.x += bv.x; v.y += bv.y; v.z += bv.z; v.w += bv.w;
    if (ACT == 0) {
      v.x = v.x > 0.f ? v.x : expm1f(v.x);
      v.y = v.y > 0.f ? v.y : expm1f(v.y);
      v.z = v.z > 0.f ? v.z : expm1f(v.z);
      v.w = v.w > 0.f ? v.w : expm1f(v.w);
    } else {
      float m = fmaxf(fmaxf(v.x, v.y), fmaxf(v.z, v.w));
      #pragma unroll
      for (int off = 16; off >= 1; off >>= 1) m = fmaxf(m, __shfl_xor(m, off));
      v.x = expf(v.x - m);
      v.y = expf(v.y - m);
      v.z = expf(v.z - m);
      v.w = expf(v.w - m);
      float s = v.x + v.y + v.z + v.w;
      #pragma unroll
      for (int off = 16; off >= 1; off >>= 1) s += __shfl_xor(s, off);
      const float inv = 1.0f / s;
      v.x *= inv; v.y *= inv; v.z *= inv; v.w *= inv;
    }
    const size_t row = (size_t)(brow + tr * 4 + i);
    *reinterpret_cast<float4*>(out + row * DIM + c0) = v;
    if (ACT == 0 && fb_out != nullptr) {
      const int dg = deg_src[row];
      const float sn = rsqrtf((float)(dg > 0 ? dg : 1));
      ushort4 o;
      o.x = f2bf(v.x * sn);
      o.y = f2bf(v.y * sn);
      o.z = f2bf(v.z * sn);
      o.w = f2bf(v.w * sn);
      *reinterpret_cast<ushort4*>(fb_out + row * DIM + c0) = o;
    }
  }
}

// ===========================================================================
// FALLBACK 1 (round-6): atomic padded-CSR build
// ===========================================================================
__global__ void k_build(const int* __restrict__ esrc, const int* __restrict__ edst,
                        int* __restrict__ deg_src, int* __restrict__ cnt,
                        unsigned* __restrict__ csr) {
  const int i = blockIdx.x * blockDim.x + threadIdx.x;
  if (i < N_EDGES) {
    const int s = esrc[i];
    const int d = edst[i];
    atomicAdd(&deg_src[s], 1);
    const int pos = atomicAdd(&cnt[d], 1);
    csr[(size_t)d * SLOTS + pos] = (unsigned)s << 8;
  }
}

// ===========================================================================
// FALLBACK 2 (round-5): compact CSR path
// ===========================================================================
__global__ void k_hist(const int* __restrict__ esrc, const int* __restrict__ edst,
                       int* __restrict__ deg_src, int* __restrict__ deg_dst) {
  const int i = blockIdx.x * blockDim.x + threadIdx.x;
  if (i < N_EDGES) {
    atomicAdd(&deg_src[esrc[i]], 1);
    atomicAdd(&deg_dst[edst[i]], 1);
  }
}

__global__ void k_bsum(const int* __restrict__ deg_dst, float* __restrict__ dst_norm,
                       int* __restrict__ bsum) {
  __shared__ int ws[4];
  const int tid  = threadIdx.x;
  const int base = blockIdx.x * 1024;
  int s = 0;
  #pragma unroll
  for (int t = 0; t < 4; ++t) {
    const int i = base + t * 256 + tid;
    const int d = deg_dst[i];
    s += d;
    dst_norm[i] = rsqrtf((float)(d > 0 ? d : 1));
  }
  #pragma unroll
  for (int off = 32; off >= 1; off >>= 1) s += __shfl_down(s, off);
  if ((tid & 63) == 0) ws[tid >> 6] = s;
  __syncthreads();
  if (tid == 0) bsum[blockIdx.x] = ws[0] + ws[1] + ws[2] + ws[3];
}

__global__ void k_bscan(const int* __restrict__ bsum, int* __restrict__ bpre) {
  const int tid = threadIdx.x;
  const int v = (tid < 100) ? bsum[tid] : 0;
  int s = v;
  #pragma unroll
  for (int off = 1; off < 64; off <<= 1) {
    const int t = __shfl_up(s, off);
    if ((tid & 63) >= off) s += t;
  }
  __shared__ int w0;
  if (tid == 63) w0 = s;
  __syncthreads();
  if (tid >= 64) s += w0;
  if (tid < 100) bpre[tid] = s - v;
}

__global__ void k_rowoff(const int* __restrict__ deg_dst, const int* __restrict__ bpre,
                         int* __restrict__ row_off, int* __restrict__ cursor) {
  __shared__ int wsum[16];
  const int tid  = threadIdx.x;
  const int lane = tid & 63;
  const int wid  = tid >> 6;
  const int i = blockIdx.x * 1024 + tid;
  const int d = deg_dst[i];
  int v = d;
  #pragma unroll
  for (int off = 1; off < 64; off <<= 1) {
    const int t = __shfl_up(v, off);
    if (lane >= off) v += t;
  }
  if (lane == 63) wsum[wid] = v;
  __syncthreads();
  if (tid < 16) {
    int w = wsum[tid];
    #pragma unroll
    for (int off = 1; off < 16; off <<= 1) {
      const int t = __shfl_up(w, off);
      if (tid >= off) w += t;
    }
    wsum[tid] = w;
  }
  __syncthreads();
  const int excl = bpre[blockIdx.x] + (wid > 0 ? wsum[wid - 1] : 0) + v - d;
  row_off[i] = excl;
  cursor[i]  = excl;
  if (i == N_NODES - 1) row_off[N_NODES] = excl + d;
}

__global__ void k_fill(const int* __restrict__ esrc, const int* __restrict__ edst,
                       const int* __restrict__ deg_src, int* __restrict__ cursor,
                       unsigned* __restrict__ csr_pk, int shift) {
  const int i = blockIdx.x * blockDim.x + threadIdx.x;
  if (i < N_EDGES) {
    const int s  = esrc[i];
    const int dg = deg_src[s];
    const int pos = atomicAdd(&cursor[edst[i]], 1);
    csr_pk[pos] = ((unsigned)s << shift) | ((unsigned)(dg > 63 ? 63 : dg) << 26);
  }
}

__global__ void k_cvt(const float* __restrict__ in, unsigned short* __restrict__ out) {
  const int i = blockIdx.x * blockDim.x + threadIdx.x;
  const float4 v = reinterpret_cast<const float4*>(in)[i];
  ushort4 o;
  o.x = f2bf(v.x);
  o.y = f2bf(v.y);
  o.z = f2bf(v.z);
  o.w = f2bf(v.w);
  reinterpret_cast<ushort4*>(out)[i] = o;
}

template <int ACT, int BF>
__global__ __launch_bounds__(256, 8) void k_layer(
    const void* __restrict__ featv, const float* __restrict__ W,
    const float* __restrict__ bias, const int* __restrict__ row_off,
    const unsigned* __restrict__ csr_pk, const float* __restrict__ dst_norm,
    float* __restrict__ out, unsigned short* __restrict__ fbn) {
  __shared__ float agg[32][132];

  const int tid  = threadIdx.x;
  const int lane = tid & 63;
  const int wid  = tid >> 6;
  const int brow = blockIdx.x * 32;
  const char* fbase = reinterpret_cast<const char*>(featv);

  for (int r = wid; r < 32; r += 4) {
    const int gr = brow + r;
    const int e0 = row_off[gr];
    const int e1 = row_off[gr + 1];
    float acc[8];
    #pragma unroll
    for (int i = 0; i < 8; ++i) acc[i] = 0.f;

    for (int e = e0; e < e1; e += 64) {
      const int cnt = min(64, e1 - e);
      const unsigned pk = (lane < cnt) ? csr_pk[e + lane] : 0u;
      const float wgt = (lane < cnt) ? rsqrtf((float)(pk >> 26)) : 0.f;
      const int off = (int)(pk & 0x03FFFFFFu);

      if (BF) {
        const int q  = lane >> 4;
        const int li = lane & 15;
        const int nq = (cnt + 3) >> 2;
        #pragma unroll 8
        for (int j = 0; j < nq; ++j) {
          const int srcl = 4 * j + q;
          const int o    = __shfl(off, srcl);
          const float ww = __shfl(wgt, srcl);
          const uint4 d = *reinterpret_cast<const uint4*>(
              fbase + (size_t)(unsigned)o + (li << 4));
          acc[0] = fmaf(ww, bf_lo(d.x), acc[0]);
          acc[1] = fmaf(ww, bf_hi(d.x), acc[1]);
          acc[2] = fmaf(ww, bf_lo(d.y), acc[2]);
          acc[3] = fmaf(ww, bf_hi(d.y), acc[3]);
          acc[4] = fmaf(ww, bf_lo(d.z), acc[4]);
          acc[5] = fmaf(ww, bf_hi(d.z), acc[5]);
          acc[6] = fmaf(ww, bf_lo(d.w), acc[6]);
          acc[7] = fmaf(ww, bf_hi(d.w), acc[7]);
        }
      } else {
        const int q  = lane >> 5;
        const int li = lane & 31;
        const int np = (cnt + 1) >> 1;
        #pragma unroll 8
        for (int j = 0; j < np; ++j) {
          const int srcl = 2 * j + q;
          const int o    = __shfl(off, srcl);
          const float ww = __shfl(wgt, srcl);
          const float4 v = *reinterpret_cast<const float4*>(
              fbase + (size_t)(unsigned)o + (li << 4));
          acc[0] = fmaf(ww, v.x, acc[0]);
          acc[1] = fmaf(ww, v.y, acc[1]);
          acc[2] = fmaf(ww, v.z, acc[2]);
          acc[3] = fmaf(ww, v.w, acc[3]);
        }
      }
    }

    const float dn = dst_norm[gr];
    if (BF) {
      #pragma unroll
      for (int i = 0; i < 8; ++i) {
        acc[i] += __shfl_xor(acc[i], 32);
        acc[i] += __shfl_xor(acc[i], 16);
        acc[i] *= dn;
      }
      if ((lane >> 4) == 0) {
        const int li = lane & 15;
        *reinterpret_cast<float4*>(&agg[r][li * 8]) =
            make_float4(acc[0], acc[1], acc[2], acc[3]);
        *reinterpret_cast<float4*>(&agg[r][li * 8 + 4]) =
            make_float4(acc[4], acc[5], acc[6], acc[7]);
      }
    } else {
      #pragma unroll
      for (int i = 0; i < 4; ++i) {
        acc[i] += __shfl_xor(acc[i], 32);
        acc[i] *= dn;
      }
      if ((lane >> 5) == 0) {
        const int li = lane & 31;
        *reinterpret_cast<float4*>(&agg[r][li * 4]) =
            make_float4(acc[0], acc[1], acc[2], acc[3]);
      }
    }
  }
  __syncthreads();

  const int tc = tid & 31;
  const int tr = tid >> 5;
  const int c0 = tc << 2;
  const float4* Wv = reinterpret_cast<const float4*>(W);

  float4 a4[4];
  #pragma unroll
  for (int i = 0; i < 4; ++i) a4[i] = make_float4(0.f, 0.f, 0.f, 0.f);

  #pragma unroll 2
  for (int k = 0; k < DIM; k += 4) {
    float4 w4[4];
    #pragma unroll
    for (int j = 0; j < 4; ++j) w4[j] = Wv[(k + j) * 32 + tc];
    #pragma unroll
    for (int i = 0; i < 4; ++i) {
      const float4 a = *reinterpret_cast<const float4*>(&agg[tr * 4 + i][k]);
      const float av[4] = {a.x, a.y, a.z, a.w};
      #pragma unroll
      for (int j = 0; j < 4; ++j) {
        a4[i].x = fmaf(av[j], w4[j].x, a4[i].x);
        a4[i].y = fmaf(av[j], w4[j].y, a4[i].y);
        a4[i].z = fmaf(av[j], w4[j].z, a4[i].z);
        a4[i].w = fmaf(av[j], w4[j].w, a4[i].w);
      }
    }
  }

  const float4 bv = *reinterpret_cast<const float4*>(bias + c0);
  #pragma unroll
  for (int i = 0; i < 4; ++i) {
    float4 v = a4[i];
    v.x += bv.x; v.y += bv.y; v.z += bv.z; v.w += bv.w;
    if (ACT == 0) {
      v.x = v.x > 0.f ? v.x : expm1f(v.x);
      v.y = v.y > 0.f ? v.y : expm1f(v.y);
      v.z = v.z > 0.f ? v.z : expm1f(v.z);
      v.w = v.w > 0.f ? v.w : expm1f(v.w);
    } else {
      float m = fmaxf(fmaxf(v.x, v.y), fmaxf(v.z, v.w));
      #pragma unroll
      for (int off = 16; off >= 1; off >>= 1) m = fmaxf(m, __shfl_xor(m, off));
      v.x = expf(v.x - m);
      v.y = expf(v.y - m);
      v.z = expf(v.z - m);
      v.w = expf(v.w - m);
      float s = v.x + v.y + v.z + v.w;
      #pragma unroll
      for (int off = 16; off >= 1; off >>= 1) s += __shfl_xor(s, off);
      const float inv = 1.0f / s;
      v.x *= inv; v.y *= inv; v.z *= inv; v.w *= inv;
    }
    const size_t row = (size_t)(brow + tr * 4 + i);
    *reinterpret_cast<float4*>(out + row * DIM + c0) = v;
    if (ACT == 0 && fbn != nullptr) {
      ushort4 o;
      o.x = f2bf(v.x);
      o.y = f2bf(v.y);
      o.z = f2bf(v.z);
      o.w = f2bf(v.w);
      *reinterpret_cast<ushort4*>(fbn + row * DIM + c0) = o;
    }
  }
}

// ---------------------------------------------------------------------------
static inline size_t align1k(size_t x) { return (x + 1023) & ~(size_t)1023; }

extern "C" void kernel_launch(void* const* d_in, const int* in_sizes, int n_in,
                              void* d_out, int out_size, void* d_ws,
                              size_t ws_size, hipStream_t stream) {
  const float* x  = (const float*)d_in[0];
  const float* W1 = (const float*)d_in[1];
  const float* b1 = (const float*)d_in[2];
  const float* W2 = (const float*)d_in[3];
  const float* b2 = (const float*)d_in[4];
  const float* W3 = (const float*)d_in[5];
  const float* b3 = (const float*)d_in[6];
  const int* esrc = (const int*)d_in[7];
  const int* edst = (const int*)d_in[8];

  float* y1 = (float*)d_out;
  float* y2 = y1 + (size_t)N_NODES * DIM;
  float* y3 = y2 + (size_t)N_NODES * DIM;

  const size_t fb_bytes = (size_t)N_NODES * DIM * 2;  // 26.2 MB

  // ---- V2 layout ----
  {
    char* ws = (char*)d_ws;
    int* dstCur = (int*)ws;                 ws += align1k(NB * 4);
    int* srcCur = (int*)ws;                 ws += align1k(NB * 4);
    int* cnt = (int*)ws;                    ws += align1k((size_t)N_NODES * 4);
    int* deg_src = (int*)ws;                ws += align1k((size_t)N_NODES * 4);
    unsigned* csr = (unsigned*)ws;          ws += align1k((size_t)N_NODES * SLOTS * 4);
    unsigned* dstStage = (unsigned*)ws;     ws += align1k((size_t)NB * BKT_CAP * 4);
    unsigned short* srcStage = (unsigned short*)ws;
                                            ws += align1k((size_t)NB * BKT_CAP * 2);
    unsigned short* fbA = (unsigned short*)ws;  ws += fb_bytes;
    unsigned short* fbB = (unsigned short*)ws;  ws += fb_bytes;
    const size_t need_v2 = (size_t)(ws - (char*)d_ws);

    if (ws_size >= need_v2) {
      k_initcur<<<1, 256, 0, stream>>>(dstCur, srcCur);
      k_scatter<<<SC_BLOCKS, 256, 0, stream>>>(esrc, edst, dstCur, srcCur,
                                               dstStage, srcStage);
      k_csr<<<NB, 256, 0, stream>>>(dstStage, dstCur, cnt, csr);
      k_sdeg<<<NB, 256, 0, stream>>>(srcStage, srcCur, deg_src);
      k_cvt_scale<<<N_NODES * DIM / 4 / 256, 256, 0, stream>>>(x, deg_src, fbA);

      k_layer_n<0><<<N_NODES / 32, 256, 0, stream>>>(
          fbA, W1, b1, cnt, csr, deg_src, y1, fbB);
      k_layer_n<0><<<N_NODES / 32, 256, 0, stream>>>(
          fbB, W2, b2, cnt, csr, deg_src, y2, fbA);
      k_layer_n<1><<<N_NODES / 32, 256, 0, stream>>>(
          fbA, W3, b3, cnt, csr, deg_src, y3, nullptr);
      return;
    }
  }

  // ---- Fallback 1: round-6 atomic padded-CSR build ----
  {
    char* ws = (char*)d_ws;
    int* deg_src = (int*)ws;  ws += (size_t)N_NODES * 4;
    int* cnt     = (int*)ws;  ws += (size_t)N_NODES * 4;
    unsigned* csr = (unsigned*)ws;  ws += (size_t)N_NODES * SLOTS * 4;
    unsigned short* fbA = (unsigned short*)ws;  ws += fb_bytes;
    unsigned short* fbB = (unsigned short*)ws;  ws += fb_bytes;
    const size_t need_v1 = (size_t)(ws - (char*)d_ws - 2 * fb_bytes) + 2 * fb_bytes;

    if (ws_size >= need_v1) {
      (void)hipMemsetAsync(deg_src, 0, (size_t)N_NODES * 2 * sizeof(int), stream);
      k_build<<<(N_EDGES + 255) / 256, 256, 0, stream>>>(esrc, edst, deg_src,
                                                         cnt, csr);
      k_cvt_scale<<<N_NODES * DIM / 4 / 256, 256, 0, stream>>>(x, deg_src, fbA);
      k_layer_n<0><<<N_NODES / 32, 256, 0, stream>>>(
          fbA, W1, b1, cnt, csr, deg_src, y1, fbB);
      k_layer_n<0><<<N_NODES / 32, 256, 0, stream>>>(
          fbB, W2, b2, cnt, csr, deg_src, y2, fbA);
      k_layer_n<1><<<N_NODES / 32, 256, 0, stream>>>(
          fbA, W3, b3, cnt, csr, deg_src, y3, nullptr);
      return;
    }
  }

  // ---- Fallback 2: compact CSR ----
  char* ws = (char*)d_ws;
  int* deg_src = (int*)ws;        ws += (size_t)N_NODES * 4;
  int* deg_dst = (int*)ws;        ws += (size_t)N_NODES * 4;
  int* row_off = (int*)ws;        ws += (size_t)(N_NODES + 32) * 4;
  int* cursor  = (int*)ws;        ws += (size_t)N_NODES * 4;
  float* dst_norm = (float*)ws;   ws += (size_t)N_NODES * 4;
  int* bsum = (int*)ws;           ws += 128 * 4;
  int* bpre = (int*)ws;           ws += 128 * 4;
  unsigned* csr_pk = (unsigned*)ws;  ws += (size_t)N_EDGES * 4;

  const size_t prep_bytes = (size_t)(ws - (char*)d_ws);
  const bool use_bf = ws_size >= prep_bytes + 2 * fb_bytes;

  unsigned short* fbA = (unsigned short*)ws;
  unsigned short* fbB = (unsigned short*)(ws + fb_bytes);

  (void)hipMemsetAsync(deg_src, 0, (size_t)N_NODES * 2 * sizeof(int), stream);

  k_hist<<<(N_EDGES + 255) / 256, 256, 0, stream>>>(esrc, edst, deg_src, deg_dst);
  k_bsum<<<N_NODES / 1024, 256, 0, stream>>>(deg_dst, dst_norm, bsum);
  k_bscan<<<1, 128, 0, stream>>>(bsum, bpre);
  k_rowoff<<<N_NODES / 1024, 1024, 0, stream>>>(deg_dst, bpre, row_off, cursor);
  k_fill<<<(N_EDGES + 255) / 256, 256, 0, stream>>>(esrc, edst, deg_src, cursor,
                                                    csr_pk, use_bf ? 8 : 9);

  if (use_bf) {
    k_cvt<<<(N_NODES * DIM / 4 + 255) / 256, 256, 0, stream>>>(x, fbA);
    k_layer<0, 1><<<N_NODES / 32, 256, 0, stream>>>(
        fbA, W1, b1, row_off, csr_pk, dst_norm, y1, fbB);
    k_layer<0, 1><<<N_NODES / 32, 256, 0, stream>>>(
        fbB, W2, b2, row_off, csr_pk, dst_norm, y2, fbA);
    k_layer<1, 1><<<N_NODES / 32, 256, 0, stream>>>(
        fbA, W3, b3, row_off, csr_pk, dst_norm, y3, nullptr);
  } else {
    k_layer<0, 0><<<N_NODES / 32, 256, 0, stream>>>(
        x, W1, b1, row_off, csr_pk, dst_norm, y1, nullptr);
    k_layer<0, 0><<<N_NODES / 32, 256, 0, stream>>>(
        y1, W2, b2, row_off, csr_pk, dst_norm, y2, nullptr);
    k_layer<1, 0><<<N_NODES / 32, 256, 0, stream>>>(
        y2, W3, b3, row_off, csr_pk, dst_norm, y3, nullptr);
  }
}